// Round 6
// baseline (646.514 us; speedup 1.0000x reference)
//
#include <hip/hip_runtime.h>
#include <hip/hip_bf16.h>

// Problem constants (fixed by the reference)
#define NN   507904          // nodes = 8192*62
#define NE   4063232         // edges = NN*8
#define NG   8192            // graphs
#define NPG  62              // nodes per graph
#define NPBLK 1984           // NN/256 (mlp grid; 256 rows/block, 4 iters)

// Bucket sort parameters
#define NB    248            // buckets = NN/2048 (exact)
#define BRNG  2048           // nodes per bucket (bucket = dst>>11)
#define BCAP  17152          // bucket record capacity (mean 16384, +6 sigma)
#define PBCAP 31744          // padded csr capacity/bucket (8-aligned)
#define P3BLK 992            // NE/4096 (exact)
#define CSRSZ (NB * PBCAP)   // 7,872,512 ints

// ---------------------------------------------------------------- ws layout (4B units)
// OFF_R region (NN*64 units) is multiplexed:
//   [0, NN*32)              Rb bf16 rows (L1 out)
//   [NN*32, +32)            Rb sentinel row
//   OFF_GSUM (NG*64)        per-graph fp32 sums (L3 out)
//   OFF_PART (NPBLK*128)    BN partials
#define OFF_R     0
#define OFF_GSUM  (OFF_R + NN * 32 + 64)
#define OFF_PART  (OFF_GSUM + NG * 64)
#define OFF_AGGBF (OFF_R + NN * 64)          // Ab bf16 rows (+sentinel) | alias: RECS / L1 t
#define OFF_CSR   (OFF_AGGBF + NN * 32 + 32) // CSRSZ ints (padded CSR)
#define OFF_OC    (OFF_CSR + CSRSZ)          // NN int2 (off,deg)
#define OFF_BCUR  (OFF_OC + 2 * NN)          // 256 ints
#define OFF_WTB   (OFF_BCUR + 256)           // bf16 weights: 22528 ushort = 11264 units
#define OFF_SS    (OFF_WTB + 11264)          // 3 x (scale[64], shift[64])

// bf16 weight offsets (ushort units)
#define WB_W1B 0
#define WB_W2A 4096
#define WB_W2B 8192
#define WB_W3A 12288
#define WB_W3B 16384
#define WB_W1A 20480         // 64 x 32, zero-padded K (only k<4 nonzero)

typedef __attribute__((ext_vector_type(8))) short short8;
typedef __attribute__((ext_vector_type(4))) float f32x4;
typedef unsigned short ushort_t;

__device__ __forceinline__ ushort_t f2bf_bits(float f) {
  union { float f; unsigned u; } x; x.f = f;
  unsigned r = x.u + 0x7FFF + ((x.u >> 16) & 1);
  return (ushort_t)(r >> 16);
}
__device__ __forceinline__ float bfu(ushort_t u) {
  union { unsigned i; float f; } x; x.i = ((unsigned)u) << 16; return x.f;
}

// ---------------------------------------------------------------- weight prep + zero-inits
__global__ __launch_bounds__(256) void prep_weights(
    const float* __restrict__ w1a, const float* __restrict__ w1b,
    const float* __restrict__ w2a, const float* __restrict__ w2b,
    const float* __restrict__ w3a, const float* __restrict__ w3b,
    ushort_t* __restrict__ wtb, int* __restrict__ bcur,
    unsigned* __restrict__ sent1, unsigned* __restrict__ sent2,
    float* __restrict__ gsum) {
  int b = blockIdx.x, tid = threadIdx.x;
  if (b == 0) {
    // W1a [4][64] -> bf16 [n][32], zero-padded K (k<4 nonzero)
    ushort_t* d = wtb + WB_W1A;
    for (int i = tid; i < 2048; i += 256) {
      int n = i >> 5, k = i & 31;
      d[i] = (k < 4) ? f2bf_bits(w1a[k * 64 + n]) : (ushort_t)0;
    }
  } else if (b == 6) {
    bcur[tid] = 0;                       // 256 ints
    if (tid < 32) { sent1[tid] = 0; sent2[tid] = 0; }   // sentinel rows
  } else if (b >= 7) {
    // zero GSUM: 512 blocks x 1024 floats = NG*64
    float* g = gsum + (size_t)(b - 7) * 1024;
#pragma unroll
    for (int k = 0; k < 4; ++k) g[k * 256 + tid] = 0.0f;
  } else {
    const float* s; ushort_t* d;
    switch (b) {
      case 1: s = w1b; d = wtb + WB_W1B; break;
      case 2: s = w2a; d = wtb + WB_W2A; break;
      case 3: s = w2b; d = wtb + WB_W2B; break;
      case 4: s = w3a; d = wtb + WB_W3A; break;
      default: s = w3b; d = wtb + WB_W3B; break;
    }
    for (int i = tid; i < 4096; i += 256) {
      int k = i >> 6, n = i & 63;              // src [k][n]
      d[n * 64 + k] = f2bf_bits(s[i]);         // dst [n][k]
    }
  }
}

// ---------------------------------------------------------------- CSR build: phase 1 (R6-proven)
__global__ __launch_bounds__(256) void p3_bin(
    const int* __restrict__ src, const int* __restrict__ dst,
    int* __restrict__ bcur, uint2* __restrict__ recs) {
  __shared__ int histo[256];
  __shared__ int scan_s[256];
  __shared__ int base_s[256];
  __shared__ int cur_s[256];
  __shared__ uint2 buf[4096];
  const int tid = threadIdx.x;
  const int e0 = blockIdx.x * 4096;

  histo[tid] = 0;
  __syncthreads();

  int d_[16], s_[16];
#pragma unroll
  for (int k = 0; k < 16; ++k) {
    int e = e0 + k * 256 + tid;
    d_[k] = dst[e]; s_[k] = src[e];
    atomicAdd(&histo[d_[k] >> 11], 1);
  }
  __syncthreads();

  int v = histo[tid];
  scan_s[tid] = v; __syncthreads();
  for (int s = 1; s < 256; s <<= 1) {
    int add = (tid >= s) ? scan_s[tid - s] : 0;
    __syncthreads();
    scan_s[tid] += add;
    __syncthreads();
  }
  int excl = scan_s[tid] - v;
  if (tid < NB) base_s[tid] = atomicAdd(&bcur[tid], v);
  cur_s[tid] = excl;
  histo[tid] = excl;
  __syncthreads();

#pragma unroll
  for (int k = 0; k < 16; ++k) {
    int b = d_[k] >> 11;
    int p = atomicAdd(&cur_s[b], 1);
    uint2 r; r.x = (unsigned)d_[k]; r.y = (unsigned)s_[k];
    buf[p] = r;
  }
  __syncthreads();

  for (int i = tid; i < 4096; i += 256) {
    uint2 r = buf[i];
    int b = (int)(r.x >> 11);
    int g = base_s[b] + (i - histo[b]);
    if (g < BCAP) recs[(size_t)b * BCAP + g] = r;
  }
}

// ---------------------------------------------------------------- CSR build: phase 2 (R6-proven, LDS cursors)
__global__ __launch_bounds__(1024) void p4_build(
    const uint2* __restrict__ recs, const int* __restrict__ bcur,
    int* __restrict__ csr, int2* __restrict__ oc) {
  __shared__ int lcnt[2048];
  __shared__ int pscan[1024];
  __shared__ int sstart[2048];
  __shared__ int scur[2048];
  const int b = blockIdx.x, tid = threadIdx.x;
  int m = bcur[b]; if (m > BCAP) m = BCAP;
  const int cbase = b * PBCAP;
  const int nbase = b << 11;
  const uint2* rp = recs + (size_t)b * BCAP;

  lcnt[tid] = 0; lcnt[1024 + tid] = 0;
  __syncthreads();
  for (int i = tid; i < m; i += 1024)
    atomicAdd(&lcnt[rp[i].x & (BRNG - 1)], 1);
  __syncthreads();

  int a0 = lcnt[2 * tid], a1 = lcnt[2 * tid + 1];
  int p0 = (a0 + 7) & ~7, p1 = (a1 + 7) & ~7;
  int ps = p0 + p1;
  pscan[tid] = ps; __syncthreads();
  for (int s = 1; s < 1024; s <<= 1) {
    int add = (tid >= s) ? pscan[tid - s] : 0;
    __syncthreads();
    pscan[tid] += add;
    __syncthreads();
  }
  int e0 = pscan[tid] - ps;
  sstart[2 * tid] = e0;          scur[2 * tid] = e0;
  sstart[2 * tid + 1] = e0 + p0; scur[2 * tid + 1] = e0 + p0;
  __syncthreads();

  // packed (off,deg) records
  {
    int2 r0; r0.x = cbase + sstart[tid];        r0.y = lcnt[tid];
    int2 r1; r1.x = cbase + sstart[1024 + tid]; r1.y = lcnt[1024 + tid];
    oc[nbase + tid] = r0;
    oc[nbase + 1024 + tid] = r1;
  }
  __syncthreads();

  for (int i = tid; i < m; i += 1024) {
    uint2 r = rp[i];
    int p = atomicAdd(&scur[r.x & (BRNG - 1)], 1);
    csr[cbase + p] = (int)r.y;
  }
  __syncthreads();

#pragma unroll
  for (int k = 0; k < 2; ++k) {
    int i = k * 1024 + tid;
    int st = sstart[i], d = lcnt[i], p = (d + 7) & ~7;
    for (int q = d; q < p; ++q) csr[cbase + st + q] = NN;   // sentinel
  }
}

// ---------------------------------------------------------------- gather L1 (C=4)
__global__ __launch_bounds__(256) void gather1(
    const float4* __restrict__ x, const int* __restrict__ csr,
    const int2* __restrict__ oc, float4* __restrict__ tout) {
  int n = blockIdx.x * 256 + threadIdx.x;
  float4 a = x[n];
  int2 oc_ = oc[n];
  int off = oc_.x, deg = oc_.y;
  const int* cp = csr + off;
  int j = 0;
  for (; j + 4 <= deg; j += 4) {
    int s0 = cp[j], s1 = cp[j + 1], s2 = cp[j + 2], s3 = cp[j + 3];
    float4 v0 = x[s0], v1 = x[s1], v2 = x[s2], v3 = x[s3];
    a.x += v0.x + v1.x + v2.x + v3.x;
    a.y += v0.y + v1.y + v2.y + v3.y;
    a.z += v0.z + v1.z + v2.z + v3.z;
    a.w += v0.w + v1.w + v2.w + v3.w;
  }
  for (; j < deg; ++j) {
    float4 v = x[cp[j]];
    a.x += v.x; a.y += v.y; a.z += v.z; a.w += v.w;
  }
  tout[n] = a;
}

// ---------------------------------------------------------------- MFMA MLP layer 1 (fp32 t in, bf16 out)
// 256 rows/block, 4 iters, grid 1984. Coalesced C-write via zt repack.
__global__ __launch_bounds__(256) void mlp_l1(
    const float4* __restrict__ tin,
    const ushort_t* __restrict__ WaTb,   // bf16 [n][32], zero-padded K
    const float* __restrict__ ba,
    const ushort_t* __restrict__ WbTb,   // bf16 [n][64]
    const float* __restrict__ bb,
    ushort_t* __restrict__ routb,
    float* __restrict__ part) {
  __shared__ __align__(16) ushort_t zt[4096];
  __shared__ float red[512];
  const int tid = threadIdx.x;
  const int wave = tid >> 6, lane = tid & 63;
  const int col = lane & 15, quad = lane >> 4;

  short8 bWa1[4], bWb[2][4];
#pragma unroll
  for (int nt = 0; nt < 4; ++nt) {
    bWa1[nt] = *(const short8*)(WaTb + (nt * 16 + col) * 32 + quad * 8);
#pragma unroll
    for (int k0 = 0; k0 < 2; ++k0)
      bWb[k0][nt] = *(const short8*)(WbTb + (nt * 16 + col) * 64 + k0 * 32 + quad * 8);
  }
  float ba_n[4], bb_n[4];
#pragma unroll
  for (int nt = 0; nt < 4; ++nt) {
    ba_n[nt] = ba[nt * 16 + col];
    bb_n[nt] = bb[nt * 16 + col];
  }

  const int wbase = wave * 1024;
  float scol[4] = {0, 0, 0, 0}, qcol[4] = {0, 0, 0, 0};

  for (int it = 0; it < 4; ++it) {
    const int tile = blockIdx.x * 256 + it * 64 + wave * 16;

    f32x4 acc1[4];
#pragma unroll
    for (int nt = 0; nt < 4; ++nt) acc1[nt] = (f32x4){0.f, 0.f, 0.f, 0.f};

    // A-frag: m=col, k=quad*8+j; real data only k<4
    float4 t4 = tin[tile + col];
    short8 az = {0, 0, 0, 0, 0, 0, 0, 0};
    if (quad == 0) {
      az[0] = (short)f2bf_bits(t4.x);
      az[1] = (short)f2bf_bits(t4.y);
      az[2] = (short)f2bf_bits(t4.z);
      az[3] = (short)f2bf_bits(t4.w);
    }
#pragma unroll
    for (int nt = 0; nt < 4; ++nt)
      acc1[nt] = __builtin_amdgcn_mfma_f32_16x16x32_bf16(az, bWa1[nt], acc1[nt], 0, 0, 0);

    // relu -> bf16 -> wave-private swizzled LDS (C-layout write, A-layout read)
#pragma unroll
    for (int nt = 0; nt < 4; ++nt) {
      int oblk = nt * 2 + (col >> 3);
#pragma unroll
      for (int r = 0; r < 4; ++r) {
        int row = quad * 4 + r;
        float z = fmaxf(acc1[nt][r] + ba_n[nt], 0.0f);
        zt[wbase + row * 64 + (((oblk ^ (row & 7)) << 3) | (col & 7))] = f2bf_bits(z);
      }
    }
    short8 az0 = *(const short8*)&zt[wbase + col * 64 + ((quad ^ (col & 7)) << 3)];
    short8 az1 = *(const short8*)&zt[wbase + col * 64 + (((4 + quad) ^ (col & 7)) << 3)];

    f32x4 acc2[4];
#pragma unroll
    for (int nt = 0; nt < 4; ++nt) acc2[nt] = (f32x4){0.f, 0.f, 0.f, 0.f};
#pragma unroll
    for (int nt = 0; nt < 4; ++nt) {
      acc2[nt] = __builtin_amdgcn_mfma_f32_16x16x32_bf16(az0, bWb[0][nt], acc2[nt], 0, 0, 0);
      acc2[nt] = __builtin_amdgcn_mfma_f32_16x16x32_bf16(az1, bWb[1][nt], acc2[nt], 0, 0, 0);
    }
    // relu -> bf16 -> zt repack (same swizzle), then coalesced 32B/lane store
#pragma unroll
    for (int nt = 0; nt < 4; ++nt) {
      int oblk = nt * 2 + (col >> 3);
#pragma unroll
      for (int r = 0; r < 4; ++r) {
        int rw = quad * 4 + r;
        float v = fmaxf(acc2[nt][r] + bb_n[nt], 0.0f);
        zt[wbase + rw * 64 + (((oblk ^ (rw & 7)) << 3) | (col & 7))] = f2bf_bits(v);
        scol[nt] += v; qcol[nt] += v * v;
      }
    }
    {
      const int R = lane >> 2, sp = lane & 3;
      short8 w0 = *(const short8*)&zt[wbase + R * 64 + (((sp * 2) ^ (R & 7)) << 3)];
      short8 w1 = *(const short8*)&zt[wbase + R * 64 + (((sp * 2 + 1) ^ (R & 7)) << 3)];
      ushort_t* dst = routb + (size_t)(tile + R) * 64 + sp * 16;
      *(short8*)dst = w0;
      *(short8*)(dst + 8) = w1;
    }
  }

#pragma unroll
  for (int nt = 0; nt < 4; ++nt) {
    float s = scol[nt], q = qcol[nt];
    s += __shfl_xor(s, 16); s += __shfl_xor(s, 32);
    q += __shfl_xor(q, 16); q += __shfl_xor(q, 32);
    if (quad == 0) {
      red[wave * 128 + nt * 16 + col] = s;
      red[wave * 128 + 64 + nt * 16 + col] = q;
    }
  }
  __syncthreads();
  if (tid < 128)
    part[blockIdx.x * 128 + tid] =
        red[tid] + red[128 + tid] + red[256 + tid] + red[384 + tid];
}

// ---------------------------------------------------------------- FUSED gather + MFMA MLP (L2/L3)
// GS=false (L2): writes bf16 rows via zt repack (coalesced full-line stores).
// GS=true  (L3): no row output; per-graph sums via LDS + global atomics.
template <bool GS>
__global__ __launch_bounds__(256) void mlp_fused(
    const ushort_t* __restrict__ h,
    const int* __restrict__ csr, const int2* __restrict__ oc,
    const float* __restrict__ ss,
    const ushort_t* __restrict__ WaTb,   // bf16 [n][64]
    const float* __restrict__ ba,
    const ushort_t* __restrict__ WbTb,   // bf16 [n][64]
    const float* __restrict__ bb,
    ushort_t* __restrict__ routb, float* __restrict__ gsum_g,
    float* __restrict__ part) {
  __shared__ __align__(16) ushort_t zt[4096];
  __shared__ float red[512];
  __shared__ float ssl[128];
  __shared__ float gsum[GS ? 384 : 1];   // 6 graphs x 64 ch
  const int tid = threadIdx.x;
  const int wave = tid >> 6, lane = tid & 63;
  const int col = lane & 15, quad = lane >> 4;
  if (tid < 128) ssl[tid] = ss[tid];
  const int g0 = (blockIdx.x * 256) / 62;   // first graph touched by block
  if (GS) {
    for (int i = tid; i < 384; i += 256) gsum[i] = 0.0f;
  }

  short8 bWa[2][4], bWb[2][4];
#pragma unroll
  for (int nt = 0; nt < 4; ++nt) {
#pragma unroll
    for (int k0 = 0; k0 < 2; ++k0) {
      bWa[k0][nt] = *(const short8*)(WaTb + (nt * 16 + col) * 64 + k0 * 32 + quad * 8);
      bWb[k0][nt] = *(const short8*)(WbTb + (nt * 16 + col) * 64 + k0 * 32 + quad * 8);
    }
  }
  float ba_n[4], bb_n[4];
#pragma unroll
  for (int nt = 0; nt < 4; ++nt) {
    ba_n[nt] = ba[nt * 16 + col];
    bb_n[nt] = bb[nt * 16 + col];
  }
  __syncthreads();   // ssl (+gsum) ready

  const float* scA = ssl + quad * 8;        // sc channels kA = quad*8+e
  const float* scB = ssl + 32 + quad * 8;   // sc channels kB = 32+quad*8+e
  const float* sfA = ssl + 64 + quad * 8;
  const float* sfB = ssl + 96 + quad * 8;

  const int wbase = wave * 1024;
  float scol[4] = {0, 0, 0, 0}, qcol[4] = {0, 0, 0, 0};

  for (int it = 0; it < 4; ++it) {
    const int tile = blockIdx.x * 256 + it * 64 + wave * 16;
    const int row = tile + col;
    const int2 o = oc[row];

    // self row (eps=0 GIN)
    const ushort_t* hp = h + (size_t)(unsigned)row * 64u + quad * 8;
    short8 sl0 = *(const short8*)hp;
    short8 sl1 = *(const short8*)(hp + 32);
    float accA[8], accB[8];
#pragma unroll
    for (int e = 0; e < 8; ++e) {
      accA[e] = bfu((ushort_t)sl0[e]);
      accB[e] = bfu((ushort_t)sl1[e]);
    }

    const int chunks = (o.y + 7) >> 3;
    for (int c = 0; c < chunks; ++c) {
      const int* cp = csr + o.x + (c << 3);
      int4 i0 = *(const int4*)cp;
      int4 i1 = *(const int4*)(cp + 4);
      int idx[8] = {i0.x, i0.y, i0.z, i0.w, i1.x, i1.y, i1.z, i1.w};
#pragma unroll
      for (int j = 0; j < 8; ++j) {
        const ushort_t* p = h + (size_t)(unsigned)idx[j] * 64u + quad * 8;
        short8 l0 = *(const short8*)p;
        short8 l1 = *(const short8*)(p + 32);
#pragma unroll
        for (int e = 0; e < 8; ++e) {
          accA[e] += bfu((ushort_t)l0[e]);
          accB[e] += bfu((ushort_t)l1[e]);
        }
      }
    }

    // folded BN of previous layer: t = sc*acc + (deg+1)*sf  (sentinels add 0)
    const float m1 = (float)(o.y + 1);
    short8 a0, a1;
#pragma unroll
    for (int e = 0; e < 8; ++e) {
      a0[e] = (short)f2bf_bits(fmaf(scA[e], accA[e], m1 * sfA[e]));
      a1[e] = (short)f2bf_bits(fmaf(scB[e], accB[e], m1 * sfB[e]));
    }

    f32x4 acc1[4];
#pragma unroll
    for (int nt = 0; nt < 4; ++nt) acc1[nt] = (f32x4){0.f, 0.f, 0.f, 0.f};
#pragma unroll
    for (int nt = 0; nt < 4; ++nt) {
      acc1[nt] = __builtin_amdgcn_mfma_f32_16x16x32_bf16(a0, bWa[0][nt], acc1[nt], 0, 0, 0);
      acc1[nt] = __builtin_amdgcn_mfma_f32_16x16x32_bf16(a1, bWa[1][nt], acc1[nt], 0, 0, 0);
    }

    // relu -> bf16 -> wave-private swizzled LDS (C-layout write, A-layout read)
#pragma unroll
    for (int nt = 0; nt < 4; ++nt) {
      int oblk = nt * 2 + (col >> 3);
#pragma unroll
      for (int r = 0; r < 4; ++r) {
        int rw = quad * 4 + r;
        float z = fmaxf(acc1[nt][r] + ba_n[nt], 0.0f);
        zt[wbase + rw * 64 + (((oblk ^ (rw & 7)) << 3) | (col & 7))] = f2bf_bits(z);
      }
    }
    short8 az0 = *(const short8*)&zt[wbase + col * 64 + ((quad ^ (col & 7)) << 3)];
    short8 az1 = *(const short8*)&zt[wbase + col * 64 + (((4 + quad) ^ (col & 7)) << 3)];

    f32x4 acc2[4];
#pragma unroll
    for (int nt = 0; nt < 4; ++nt) acc2[nt] = (f32x4){0.f, 0.f, 0.f, 0.f};
#pragma unroll
    for (int nt = 0; nt < 4; ++nt) {
      acc2[nt] = __builtin_amdgcn_mfma_f32_16x16x32_bf16(az0, bWb[0][nt], acc2[nt], 0, 0, 0);
      acc2[nt] = __builtin_amdgcn_mfma_f32_16x16x32_bf16(az1, bWb[1][nt], acc2[nt], 0, 0, 0);
    }

    if (GS) {
      // per-graph accumulation of raw z3 (BN3 applied later in fc_out)
#pragma unroll
      for (int nt = 0; nt < 4; ++nt) {
#pragma unroll
        for (int r = 0; r < 4; ++r) {
          int rw = tile + quad * 4 + r;
          float v = fmaxf(acc2[nt][r] + bb_n[nt], 0.0f);
          scol[nt] += v; qcol[nt] += v * v;
          int gl = rw / 62 - g0;
          atomicAdd(&gsum[gl * 64 + nt * 16 + col], v);
        }
      }
    } else {
      // relu -> bf16 -> zt repack, then coalesced 32B/lane store
#pragma unroll
      for (int nt = 0; nt < 4; ++nt) {
        int oblk = nt * 2 + (col >> 3);
#pragma unroll
        for (int r = 0; r < 4; ++r) {
          int rw = quad * 4 + r;
          float v = fmaxf(acc2[nt][r] + bb_n[nt], 0.0f);
          zt[wbase + rw * 64 + (((oblk ^ (rw & 7)) << 3) | (col & 7))] = f2bf_bits(v);
          scol[nt] += v; qcol[nt] += v * v;
        }
      }
      const int R = lane >> 2, sp = lane & 3;
      short8 w0 = *(const short8*)&zt[wbase + R * 64 + (((sp * 2) ^ (R & 7)) << 3)];
      short8 w1 = *(const short8*)&zt[wbase + R * 64 + (((sp * 2 + 1) ^ (R & 7)) << 3)];
      ushort_t* dst = routb + (size_t)(tile + R) * 64 + sp * 16;
      *(short8*)dst = w0;
      *(short8*)(dst + 8) = w1;
    }
  }

#pragma unroll
  for (int nt = 0; nt < 4; ++nt) {
    float s = scol[nt], q = qcol[nt];
    s += __shfl_xor(s, 16); s += __shfl_xor(s, 32);
    q += __shfl_xor(q, 16); q += __shfl_xor(q, 32);
    if (quad == 0) {
      red[wave * 128 + nt * 16 + col] = s;
      red[wave * 128 + 64 + nt * 16 + col] = q;
    }
  }
  __syncthreads();
  if (tid < 128)
    part[blockIdx.x * 128 + tid] =
        red[tid] + red[128 + tid] + red[256 + tid] + red[384 + tid];

  if (GS) {
    // flush per-block graph sums (boundary graphs merged via atomics)
    for (int i = tid; i < 384; i += 256) {
      int g = g0 + (i >> 6);
      float v = gsum[i];
      if (g < NG && v != 0.0f) atomicAdd(&gsum_g[(size_t)g * 64 + (i & 63)], v);
    }
  }
}

// ---------------------------------------------------------------- BN reduce+finalize (merged)
// grid = 64; block c reduces sum (col c) and sumsq (col 64+c), writes ss.
__global__ __launch_bounds__(256) void reduce_finalize(
    const float* __restrict__ part, const float* __restrict__ gma,
    const float* __restrict__ bta, float* __restrict__ ss) {
  __shared__ double sh[512];
  const int c = blockIdx.x, tid = threadIdx.x;
  double a = 0.0, b = 0.0;
  for (int blk = tid; blk < NPBLK; blk += 256) {
    a += (double)part[blk * 128 + c];
    b += (double)part[blk * 128 + 64 + c];
  }
  sh[tid] = a; sh[256 + tid] = b;
  __syncthreads();
  for (int s = 128; s; s >>= 1) {
    if (tid < s) { sh[tid] += sh[tid + s]; sh[256 + tid] += sh[256 + tid + s]; }
    __syncthreads();
  }
  if (tid == 0) {
    double mean = sh[0] / (double)NN;
    double var = sh[256] / (double)NN - mean * mean;
    double sc = (double)gma[c] / sqrt(var + 1e-5);
    ss[c] = (float)sc;
    ss[64 + c] = (float)((double)bta[c] - mean * sc);
  }
}

// ---------------------------------------------------------------- final fc from per-graph sums
// pooled = sc3 * S_g + 62*sf3 ; out = pooled @ Wfc + bfc. 4 graphs/block.
__global__ __launch_bounds__(256) void fc_out(
    const float* __restrict__ gsum_g, const float* __restrict__ ss,
    const float* __restrict__ wfc, const float* __restrict__ bfc,
    float* __restrict__ out) {
  const int lane = threadIdx.x & 63;
  const int g = blockIdx.x * 4 + (threadIdx.x >> 6);
  const int c = lane;
  float s = gsum_g[(size_t)g * 64 + c];
  float pooled = fmaf(ss[c], s, (float)NPG * ss[64 + c]);
#pragma unroll
  for (int j = 0; j < 3; ++j) {
    float v = pooled * wfc[c * 3 + j];
    for (int m = 32; m; m >>= 1) v += __shfl_xor(v, m);
    if (c == 0) out[g * 3 + j] = v + bfc[j];
  }
}

// ---------------------------------------------------------------- launch
extern "C" void kernel_launch(void* const* d_in, const int* in_sizes, int n_in,
                              void* d_out, int out_size, void* d_ws, size_t ws_size,
                              hipStream_t stream) {
  const float* x    = (const float*)d_in[0];
  const int*   srcE = (const int*)d_in[1];
  const int*   dstE = (const int*)d_in[2];
  const float* W1a = (const float*)d_in[4],  *b1a = (const float*)d_in[5];
  const float* W1b = (const float*)d_in[6],  *b1b = (const float*)d_in[7];
  const float* g1  = (const float*)d_in[8],  *be1 = (const float*)d_in[9];
  const float* W2a = (const float*)d_in[10], *b2a = (const float*)d_in[11];
  const float* W2b = (const float*)d_in[12], *b2b = (const float*)d_in[13];
  const float* g2  = (const float*)d_in[14], *be2 = (const float*)d_in[15];
  const float* W3a = (const float*)d_in[16], *b3a = (const float*)d_in[17];
  const float* W3b = (const float*)d_in[18], *b3b = (const float*)d_in[19];
  const float* g3  = (const float*)d_in[20], *be3 = (const float*)d_in[21];
  const float* Wfc = (const float*)d_in[22], *bfc = (const float*)d_in[23];

  float* ws = (float*)d_ws;
  ushort_t* Rb     = (ushort_t*)(ws + OFF_R);    // bf16 rows + sentinel (L1 out)
  float*    GSUM   = ws + OFF_GSUM;              // per-graph sums (L3 out)
  float*    PART   = ws + OFF_PART;
  ushort_t* Ab     = (ushort_t*)(ws + OFF_AGGBF);// bf16 rows + sentinel (L2 out)
  void*     T1     = (void*)(ws + OFF_AGGBF);    // alias: L1 gather out (fp32 t)
  uint2*    RECS   = (uint2*)(ws + OFF_AGGBF);   // alias: dead before gather1
  int*      CSR    = (int*)(ws + OFF_CSR);
  int2*     OC     = (int2*)(ws + OFF_OC);
  int*      BCUR   = (int*)(ws + OFF_BCUR);
  ushort_t* WTB    = (ushort_t*)(ws + OFF_WTB);
  float*    SS     = ws + OFF_SS;

  // weights + BCUR + sentinels + GSUM zero in one dispatch
  prep_weights<<<519, 256, 0, stream>>>(W1a, W1b, W2a, W2b, W3a, W3b, WTB, BCUR,
                                        (unsigned*)(Rb + (size_t)NN * 64),
                                        (unsigned*)(Ab + (size_t)NN * 64),
                                        GSUM);

  // ---- CSR build (bucket sort, LDS cursors, padded to 8 with sentinel NN)
  p3_bin<<<P3BLK, 256, 0, stream>>>(srcE, dstE, BCUR, RECS);
  p4_build<<<NB, 1024, 0, stream>>>(RECS, BCUR, CSR, OC);

  // ---- layer 1: gather(x) -> T1(fp32 t), MLP -> Rb(bf16)
  gather1<<<NN / 256, 256, 0, stream>>>((const float4*)x, CSR, OC, (float4*)T1);
  mlp_l1<<<NPBLK, 256, 0, stream>>>((const float4*)T1, WTB + WB_W1A, b1a,
                                    WTB + WB_W1B, b1b, Rb, PART);
  reduce_finalize<<<64, 256, 0, stream>>>(PART, g1, be1, SS + 0);

  // ---- layer 2 (fused): read Rb (random), write Ab (bf16, coalesced)
  mlp_fused<false><<<NPBLK, 256, 0, stream>>>(Rb, CSR, OC, SS + 0,
                                              WTB + WB_W2A, b2a,
                                              WTB + WB_W2B, b2b,
                                              Ab, nullptr, PART);
  reduce_finalize<<<64, 256, 0, stream>>>(PART, g2, be2, SS + 128);

  // ---- layer 3 (fused): read Ab (random), emit per-graph sums (no row out)
  mlp_fused<true><<<NPBLK, 256, 0, stream>>>(Ab, CSR, OC, SS + 128,
                                             WTB + WB_W3A, b3a,
                                             WTB + WB_W3B, b3b,
                                             nullptr, GSUM, PART);
  reduce_finalize<<<64, 256, 0, stream>>>(PART, g3, be3, SS + 256);

  // ---- classifier from per-graph sums
  fc_out<<<NG / 4, 256, 0, stream>>>(GSUM, SS + 256, Wfc, bfc, (float*)d_out);
}

// Round 7
// 644.403 us; speedup vs baseline: 1.0033x; 1.0033x over previous
//
#include <hip/hip_runtime.h>
#include <hip/hip_bf16.h>

// Problem constants (fixed by the reference)
#define NN   507904          // nodes = 8192*62
#define NE   4063232         // edges = NN*8
#define NG   8192            // graphs
#define NPG  62              // nodes per graph
#define NPBLK 1984           // NN/256 (mlp grid; 256 rows/block, 4 iters)

// Bucket sort parameters
#define NB    248            // buckets = NN/2048 (exact)
#define BRNG  2048           // nodes per bucket (bucket = dst>>11)
#define BCAP  17152          // bucket record capacity (mean 16384, +6 sigma)
#define PBCAP 31744          // padded csr capacity/bucket (8-aligned)
#define P3BLK 992            // NE/4096 (exact)
#define CSRSZ (NB * PBCAP)   // 7,872,512 ints

// ---------------------------------------------------------------- ws layout (4B units)
// OFF_R region (NN*64 units) is multiplexed:
//   [0, NN*32)              Rb bf16 rows (L1 out)
//   [NN*32, +32)            Rb sentinel row
//   OFF_GSUM (NG*64)        per-graph fp32 sums (L3 out)
//   OFF_PART (NPBLK*128)    BN partials
#define OFF_R     0
#define OFF_GSUM  (OFF_R + NN * 32 + 64)
#define OFF_PART  (OFF_GSUM + NG * 64)
#define OFF_AGGBF (OFF_R + NN * 64)          // Ab bf16 rows (+sentinel) | alias: RECS / L1 t
#define OFF_CSR   (OFF_AGGBF + NN * 32 + 32) // CSRSZ ints (padded CSR)
#define OFF_OC    (OFF_CSR + CSRSZ)          // NN int2 (off,deg)
#define OFF_BCUR  (OFF_OC + 2 * NN)          // 256 ints
#define OFF_WTB   (OFF_BCUR + 256)           // bf16 weights: 22528 ushort = 11264 units
#define OFF_SS    (OFF_WTB + 11264)          // 3 x (scale[64], shift[64])

// bf16 weight offsets (ushort units)
#define WB_W1B 0
#define WB_W2A 4096
#define WB_W2B 8192
#define WB_W3A 12288
#define WB_W3B 16384
#define WB_W1A 20480         // 64 x 32, zero-padded K (only k<4 nonzero)

typedef __attribute__((ext_vector_type(8))) short short8;
typedef __attribute__((ext_vector_type(4))) float f32x4;
typedef unsigned short ushort_t;

__device__ __forceinline__ ushort_t f2bf_bits(float f) {
  union { float f; unsigned u; } x; x.f = f;
  unsigned r = x.u + 0x7FFF + ((x.u >> 16) & 1);
  return (ushort_t)(r >> 16);
}
__device__ __forceinline__ float bfu(ushort_t u) {
  union { unsigned i; float f; } x; x.i = ((unsigned)u) << 16; return x.f;
}

// ---------------------------------------------------------------- weight prep + zero-inits
__global__ __launch_bounds__(256) void prep_weights(
    const float* __restrict__ w1a, const float* __restrict__ w1b,
    const float* __restrict__ w2a, const float* __restrict__ w2b,
    const float* __restrict__ w3a, const float* __restrict__ w3b,
    ushort_t* __restrict__ wtb, int* __restrict__ bcur,
    unsigned* __restrict__ sent1, unsigned* __restrict__ sent2,
    float* __restrict__ gsum) {
  int b = blockIdx.x, tid = threadIdx.x;
  if (b == 0) {
    // W1a [4][64] -> bf16 [n][32], zero-padded K (k<4 nonzero)
    ushort_t* d = wtb + WB_W1A;
    for (int i = tid; i < 2048; i += 256) {
      int n = i >> 5, k = i & 31;
      d[i] = (k < 4) ? f2bf_bits(w1a[k * 64 + n]) : (ushort_t)0;
    }
  } else if (b == 6) {
    bcur[tid] = 0;                       // 256 ints
    if (tid < 32) { sent1[tid] = 0; sent2[tid] = 0; }   // sentinel rows
  } else if (b >= 7) {
    // zero GSUM: 512 blocks x 1024 floats = NG*64
    float* g = gsum + (size_t)(b - 7) * 1024;
#pragma unroll
    for (int k = 0; k < 4; ++k) g[k * 256 + tid] = 0.0f;
  } else {
    const float* s; ushort_t* d;
    switch (b) {
      case 1: s = w1b; d = wtb + WB_W1B; break;
      case 2: s = w2a; d = wtb + WB_W2A; break;
      case 3: s = w2b; d = wtb + WB_W2B; break;
      case 4: s = w3a; d = wtb + WB_W3A; break;
      default: s = w3b; d = wtb + WB_W3B; break;
    }
    for (int i = tid; i < 4096; i += 256) {
      int k = i >> 6, n = i & 63;              // src [k][n]
      d[n * 64 + k] = f2bf_bits(s[i]);         // dst [n][k]
    }
  }
}

// ---------------------------------------------------------------- CSR build: phase 1 (R6-proven)
__global__ __launch_bounds__(256) void p3_bin(
    const int* __restrict__ src, const int* __restrict__ dst,
    int* __restrict__ bcur, uint2* __restrict__ recs) {
  __shared__ int histo[256];
  __shared__ int scan_s[256];
  __shared__ int base_s[256];
  __shared__ int cur_s[256];
  __shared__ uint2 buf[4096];
  const int tid = threadIdx.x;
  const int e0 = blockIdx.x * 4096;

  histo[tid] = 0;
  __syncthreads();

  int d_[16], s_[16];
#pragma unroll
  for (int k = 0; k < 16; ++k) {
    int e = e0 + k * 256 + tid;
    d_[k] = dst[e]; s_[k] = src[e];
    atomicAdd(&histo[d_[k] >> 11], 1);
  }
  __syncthreads();

  int v = histo[tid];
  scan_s[tid] = v; __syncthreads();
  for (int s = 1; s < 256; s <<= 1) {
    int add = (tid >= s) ? scan_s[tid - s] : 0;
    __syncthreads();
    scan_s[tid] += add;
    __syncthreads();
  }
  int excl = scan_s[tid] - v;
  if (tid < NB) base_s[tid] = atomicAdd(&bcur[tid], v);
  cur_s[tid] = excl;
  histo[tid] = excl;
  __syncthreads();

#pragma unroll
  for (int k = 0; k < 16; ++k) {
    int b = d_[k] >> 11;
    int p = atomicAdd(&cur_s[b], 1);
    uint2 r; r.x = (unsigned)d_[k]; r.y = (unsigned)s_[k];
    buf[p] = r;
  }
  __syncthreads();

  for (int i = tid; i < 4096; i += 256) {
    uint2 r = buf[i];
    int b = (int)(r.x >> 11);
    int g = base_s[b] + (i - histo[b]);
    if (g < BCAP) recs[(size_t)b * BCAP + g] = r;
  }
}

// ---------------------------------------------------------------- CSR build: phase 2 (R6-proven, LDS cursors)
__global__ __launch_bounds__(1024) void p4_build(
    const uint2* __restrict__ recs, const int* __restrict__ bcur,
    int* __restrict__ csr, int2* __restrict__ oc) {
  __shared__ int lcnt[2048];
  __shared__ int pscan[1024];
  __shared__ int sstart[2048];
  __shared__ int scur[2048];
  const int b = blockIdx.x, tid = threadIdx.x;
  int m = bcur[b]; if (m > BCAP) m = BCAP;
  const int cbase = b * PBCAP;
  const int nbase = b << 11;
  const uint2* rp = recs + (size_t)b * BCAP;

  lcnt[tid] = 0; lcnt[1024 + tid] = 0;
  __syncthreads();
  for (int i = tid; i < m; i += 1024)
    atomicAdd(&lcnt[rp[i].x & (BRNG - 1)], 1);
  __syncthreads();

  int a0 = lcnt[2 * tid], a1 = lcnt[2 * tid + 1];
  int p0 = (a0 + 7) & ~7, p1 = (a1 + 7) & ~7;
  int ps = p0 + p1;
  pscan[tid] = ps; __syncthreads();
  for (int s = 1; s < 1024; s <<= 1) {
    int add = (tid >= s) ? pscan[tid - s] : 0;
    __syncthreads();
    pscan[tid] += add;
    __syncthreads();
  }
  int e0 = pscan[tid] - ps;
  sstart[2 * tid] = e0;          scur[2 * tid] = e0;
  sstart[2 * tid + 1] = e0 + p0; scur[2 * tid + 1] = e0 + p0;
  __syncthreads();

  // packed (off,deg) records
  {
    int2 r0; r0.x = cbase + sstart[tid];        r0.y = lcnt[tid];
    int2 r1; r1.x = cbase + sstart[1024 + tid]; r1.y = lcnt[1024 + tid];
    oc[nbase + tid] = r0;
    oc[nbase + 1024 + tid] = r1;
  }
  __syncthreads();

  for (int i = tid; i < m; i += 1024) {
    uint2 r = rp[i];
    int p = atomicAdd(&scur[r.x & (BRNG - 1)], 1);
    csr[cbase + p] = (int)r.y;
  }
  __syncthreads();

#pragma unroll
  for (int k = 0; k < 2; ++k) {
    int i = k * 1024 + tid;
    int st = sstart[i], d = lcnt[i], p = (d + 7) & ~7;
    for (int q = d; q < p; ++q) csr[cbase + st + q] = NN;   // sentinel
  }
}

// ---------------------------------------------------------------- gather L1 (C=4)
__global__ __launch_bounds__(256) void gather1(
    const float4* __restrict__ x, const int* __restrict__ csr,
    const int2* __restrict__ oc, float4* __restrict__ tout) {
  int n = blockIdx.x * 256 + threadIdx.x;
  float4 a = x[n];
  int2 oc_ = oc[n];
  int off = oc_.x, deg = oc_.y;
  const int* cp = csr + off;
  int j = 0;
  for (; j + 4 <= deg; j += 4) {
    int s0 = cp[j], s1 = cp[j + 1], s2 = cp[j + 2], s3 = cp[j + 3];
    float4 v0 = x[s0], v1 = x[s1], v2 = x[s2], v3 = x[s3];
    a.x += v0.x + v1.x + v2.x + v3.x;
    a.y += v0.y + v1.y + v2.y + v3.y;
    a.z += v0.z + v1.z + v2.z + v3.z;
    a.w += v0.w + v1.w + v2.w + v3.w;
  }
  for (; j < deg; ++j) {
    float4 v = x[cp[j]];
    a.x += v.x; a.y += v.y; a.z += v.z; a.w += v.w;
  }
  tout[n] = a;
}

// ---------------------------------------------------------------- MFMA MLP layer 1 (fp32 t in, bf16 out)
// 256 rows/block, 4 iters, grid 1984. Coalesced C-write via zt repack.
__global__ __launch_bounds__(256) void mlp_l1(
    const float4* __restrict__ tin,
    const ushort_t* __restrict__ WaTb,   // bf16 [n][32], zero-padded K
    const float* __restrict__ ba,
    const ushort_t* __restrict__ WbTb,   // bf16 [n][64]
    const float* __restrict__ bb,
    ushort_t* __restrict__ routb,
    float* __restrict__ part) {
  __shared__ __align__(16) ushort_t zt[4096];
  __shared__ float red[512];
  const int tid = threadIdx.x;
  const int wave = tid >> 6, lane = tid & 63;
  const int col = lane & 15, quad = lane >> 4;

  short8 bWa1[4], bWb[2][4];
#pragma unroll
  for (int nt = 0; nt < 4; ++nt) {
    bWa1[nt] = *(const short8*)(WaTb + (nt * 16 + col) * 32 + quad * 8);
#pragma unroll
    for (int k0 = 0; k0 < 2; ++k0)
      bWb[k0][nt] = *(const short8*)(WbTb + (nt * 16 + col) * 64 + k0 * 32 + quad * 8);
  }
  float ba_n[4], bb_n[4];
#pragma unroll
  for (int nt = 0; nt < 4; ++nt) {
    ba_n[nt] = ba[nt * 16 + col];
    bb_n[nt] = bb[nt * 16 + col];
  }

  const int wbase = wave * 1024;
  float scol[4] = {0, 0, 0, 0}, qcol[4] = {0, 0, 0, 0};

  for (int it = 0; it < 4; ++it) {
    const int tile = blockIdx.x * 256 + it * 64 + wave * 16;

    f32x4 acc1[4];
#pragma unroll
    for (int nt = 0; nt < 4; ++nt) acc1[nt] = (f32x4){0.f, 0.f, 0.f, 0.f};

    // A-frag: m=col, k=quad*8+j; real data only k<4
    float4 t4 = tin[tile + col];
    short8 az = {0, 0, 0, 0, 0, 0, 0, 0};
    if (quad == 0) {
      az[0] = (short)f2bf_bits(t4.x);
      az[1] = (short)f2bf_bits(t4.y);
      az[2] = (short)f2bf_bits(t4.z);
      az[3] = (short)f2bf_bits(t4.w);
    }
#pragma unroll
    for (int nt = 0; nt < 4; ++nt)
      acc1[nt] = __builtin_amdgcn_mfma_f32_16x16x32_bf16(az, bWa1[nt], acc1[nt], 0, 0, 0);

    // relu -> bf16 -> wave-private swizzled LDS (C-layout write, A-layout read)
#pragma unroll
    for (int nt = 0; nt < 4; ++nt) {
      int oblk = nt * 2 + (col >> 3);
#pragma unroll
      for (int r = 0; r < 4; ++r) {
        int row = quad * 4 + r;
        float z = fmaxf(acc1[nt][r] + ba_n[nt], 0.0f);
        zt[wbase + row * 64 + (((oblk ^ (row & 7)) << 3) | (col & 7))] = f2bf_bits(z);
      }
    }
    short8 az0 = *(const short8*)&zt[wbase + col * 64 + ((quad ^ (col & 7)) << 3)];
    short8 az1 = *(const short8*)&zt[wbase + col * 64 + (((4 + quad) ^ (col & 7)) << 3)];

    f32x4 acc2[4];
#pragma unroll
    for (int nt = 0; nt < 4; ++nt) acc2[nt] = (f32x4){0.f, 0.f, 0.f, 0.f};
#pragma unroll
    for (int nt = 0; nt < 4; ++nt) {
      acc2[nt] = __builtin_amdgcn_mfma_f32_16x16x32_bf16(az0, bWb[0][nt], acc2[nt], 0, 0, 0);
      acc2[nt] = __builtin_amdgcn_mfma_f32_16x16x32_bf16(az1, bWb[1][nt], acc2[nt], 0, 0, 0);
    }
    // relu -> bf16 -> zt repack (same swizzle), then coalesced 32B/lane store
#pragma unroll
    for (int nt = 0; nt < 4; ++nt) {
      int oblk = nt * 2 + (col >> 3);
#pragma unroll
      for (int r = 0; r < 4; ++r) {
        int rw = quad * 4 + r;
        float v = fmaxf(acc2[nt][r] + bb_n[nt], 0.0f);
        zt[wbase + rw * 64 + (((oblk ^ (rw & 7)) << 3) | (col & 7))] = f2bf_bits(v);
        scol[nt] += v; qcol[nt] += v * v;
      }
    }
    {
      const int R = lane >> 2, sp = lane & 3;
      short8 w0 = *(const short8*)&zt[wbase + R * 64 + (((sp * 2) ^ (R & 7)) << 3)];
      short8 w1 = *(const short8*)&zt[wbase + R * 64 + (((sp * 2 + 1) ^ (R & 7)) << 3)];
      ushort_t* dst = routb + (size_t)(tile + R) * 64 + sp * 16;
      *(short8*)dst = w0;
      *(short8*)(dst + 8) = w1;
    }
  }

#pragma unroll
  for (int nt = 0; nt < 4; ++nt) {
    float s = scol[nt], q = qcol[nt];
    s += __shfl_xor(s, 16); s += __shfl_xor(s, 32);
    q += __shfl_xor(q, 16); q += __shfl_xor(q, 32);
    if (quad == 0) {
      red[wave * 128 + nt * 16 + col] = s;
      red[wave * 128 + 64 + nt * 16 + col] = q;
    }
  }
  __syncthreads();
  if (tid < 128)
    part[blockIdx.x * 128 + tid] =
        red[tid] + red[128 + tid] + red[256 + tid] + red[384 + tid];
}

// ---------------------------------------------------------------- FUSED gather + MFMA MLP (L2/L3)
// Weights live in LDS (stride-72 rows -> 2 lanes/bank = conflict-free);
// fragments re-read per iter via opaque offset (blocks LICM/CSE) to keep
// VGPR low. GS=false (L2): bf16 row out via zt repack. GS=true (L3):
// per-graph sums via segmented register reduction + few LDS atomics.
template <bool GS>
__global__ __launch_bounds__(256, 5) void mlp_fused(
    const ushort_t* __restrict__ h,
    const int* __restrict__ csr, const int2* __restrict__ oc,
    const float* __restrict__ ss,
    const ushort_t* __restrict__ WaTb,   // bf16 [n][64]
    const float* __restrict__ ba,
    const ushort_t* __restrict__ WbTb,   // bf16 [n][64]
    const float* __restrict__ bb,
    ushort_t* __restrict__ routb, float* __restrict__ gsum_g,
    float* __restrict__ part) {
  __shared__ __align__(16) ushort_t zt[4096];
  __shared__ __align__(16) ushort_t wa_l[4608];   // 64 rows x 72 (stride-padded)
  __shared__ __align__(16) ushort_t wb_l[4608];
  __shared__ float red[512];
  __shared__ float ssl[128];
  __shared__ float gsum[GS ? 384 : 1];   // 6 graphs x 64 ch
  const int tid = threadIdx.x;
  const int wave = tid >> 6, lane = tid & 63;
  const int col = lane & 15, quad = lane >> 4;
  if (tid < 128) ssl[tid] = ss[tid];
  const int g0 = (blockIdx.x * 256) / 62;   // first graph touched by block
  if (GS) {
    for (int i = tid; i < 384; i += 256) gsum[i] = 0.0f;
  }
  // stage weights to LDS (one-time)
  for (int i = tid; i < 4096; i += 256) {
    int n = i >> 6, k = i & 63;
    wa_l[n * 72 + k] = WaTb[i];
    wb_l[n * 72 + k] = WbTb[i];
  }

  float ba_n[4], bb_n[4];
#pragma unroll
  for (int nt = 0; nt < 4; ++nt) {
    ba_n[nt] = ba[nt * 16 + col];
    bb_n[nt] = bb[nt * 16 + col];
  }
  __syncthreads();   // ssl + weights (+gsum) ready

  const float* scA = ssl + quad * 8;        // sc channels kA = quad*8+e
  const float* scB = ssl + 32 + quad * 8;   // sc channels kB = 32+quad*8+e
  const float* sfA = ssl + 64 + quad * 8;
  const float* sfB = ssl + 96 + quad * 8;

  const int wbase = wave * 1024;
  float scol[4] = {0, 0, 0, 0}, qcol[4] = {0, 0, 0, 0};

  for (int it = 0; it < 4; ++it) {
    const int tile = blockIdx.x * 256 + it * 64 + wave * 16;
    const int row = tile + col;
    const int2 o = oc[row];

    // self row (eps=0 GIN)
    const ushort_t* hp = h + (size_t)(unsigned)row * 64u + quad * 8;
    short8 sl0 = *(const short8*)hp;
    short8 sl1 = *(const short8*)(hp + 32);
    float accA[8], accB[8];
#pragma unroll
    for (int e = 0; e < 8; ++e) {
      accA[e] = bfu((ushort_t)sl0[e]);
      accB[e] = bfu((ushort_t)sl1[e]);
    }

    const int chunks = (o.y + 7) >> 3;
    for (int c = 0; c < chunks; ++c) {
      const int* cp = csr + o.x + (c << 3);
      int4 i0 = *(const int4*)cp;
      int4 i1 = *(const int4*)(cp + 4);
      int idx[8] = {i0.x, i0.y, i0.z, i0.w, i1.x, i1.y, i1.z, i1.w};
#pragma unroll
      for (int j = 0; j < 8; ++j) {
        const ushort_t* p = h + (size_t)(unsigned)idx[j] * 64u + quad * 8;
        short8 l0 = *(const short8*)p;
        short8 l1 = *(const short8*)(p + 32);
#pragma unroll
        for (int e = 0; e < 8; ++e) {
          accA[e] += bfu((ushort_t)l0[e]);
          accB[e] += bfu((ushort_t)l1[e]);
        }
      }
    }

    // folded BN of previous layer: t = sc*acc + (deg+1)*sf  (sentinels add 0)
    const float m1 = (float)(o.y + 1);
    short8 a0, a1;
#pragma unroll
    for (int e = 0; e < 8; ++e) {
      a0[e] = (short)f2bf_bits(fmaf(scA[e], accA[e], m1 * sfA[e]));
      a1[e] = (short)f2bf_bits(fmaf(scB[e], accB[e], m1 * sfB[e]));
    }

    // opaque zero offset: blocks LICM/CSE of the LDS weight reads across
    // iters so fragments stay transient (VGPR pressure), not resident.
    int wofs = 0;
    asm volatile("" : "+v"(wofs));
    const ushort_t* wap = wa_l + wofs;
    const ushort_t* wbp = wb_l + wofs;

    f32x4 acc1[4];
#pragma unroll
    for (int nt = 0; nt < 4; ++nt) acc1[nt] = (f32x4){0.f, 0.f, 0.f, 0.f};
#pragma unroll
    for (int nt = 0; nt < 4; ++nt) {
      short8 w0 = *(const short8*)(wap + (nt * 16 + col) * 72 + quad * 8);
      short8 w1 = *(const short8*)(wap + (nt * 16 + col) * 72 + 32 + quad * 8);
      acc1[nt] = __builtin_amdgcn_mfma_f32_16x16x32_bf16(a0, w0, acc1[nt], 0, 0, 0);
      acc1[nt] = __builtin_amdgcn_mfma_f32_16x16x32_bf16(a1, w1, acc1[nt], 0, 0, 0);
    }

    // relu -> bf16 -> wave-private swizzled LDS (C-layout write, A-layout read)
#pragma unroll
    for (int nt = 0; nt < 4; ++nt) {
      int oblk = nt * 2 + (col >> 3);
#pragma unroll
      for (int r = 0; r < 4; ++r) {
        int rw = quad * 4 + r;
        float z = fmaxf(acc1[nt][r] + ba_n[nt], 0.0f);
        zt[wbase + rw * 64 + (((oblk ^ (rw & 7)) << 3) | (col & 7))] = f2bf_bits(z);
      }
    }
    short8 az0 = *(const short8*)&zt[wbase + col * 64 + ((quad ^ (col & 7)) << 3)];
    short8 az1 = *(const short8*)&zt[wbase + col * 64 + (((4 + quad) ^ (col & 7)) << 3)];

    f32x4 acc2[4];
#pragma unroll
    for (int nt = 0; nt < 4; ++nt) acc2[nt] = (f32x4){0.f, 0.f, 0.f, 0.f};
#pragma unroll
    for (int nt = 0; nt < 4; ++nt) {
      short8 w0 = *(const short8*)(wbp + (nt * 16 + col) * 72 + quad * 8);
      short8 w1 = *(const short8*)(wbp + (nt * 16 + col) * 72 + 32 + quad * 8);
      acc2[nt] = __builtin_amdgcn_mfma_f32_16x16x32_bf16(az0, w0, acc2[nt], 0, 0, 0);
      acc2[nt] = __builtin_amdgcn_mfma_f32_16x16x32_bf16(az1, w1, acc2[nt], 0, 0, 0);
    }

    if (GS) {
      // segmented per-graph reduction: a wave's 16 rows span <=2 graphs.
      const int gLo = tile / 62;
      const int rEnd = (gLo + 1) * 62;
      float vLo[4], vHi[4];
#pragma unroll
      for (int nt = 0; nt < 4; ++nt) { vLo[nt] = 0.f; vHi[nt] = 0.f; }
#pragma unroll
      for (int nt = 0; nt < 4; ++nt) {
#pragma unroll
        for (int r = 0; r < 4; ++r) {
          int rw = tile + quad * 4 + r;
          float v = fmaxf(acc2[nt][r] + bb_n[nt], 0.0f);
          scol[nt] += v; qcol[nt] += v * v;
          if (rw < rEnd) vLo[nt] += v; else vHi[nt] += v;
        }
      }
#pragma unroll
      for (int nt = 0; nt < 4; ++nt) {
        vLo[nt] += __shfl_xor(vLo[nt], 16); vLo[nt] += __shfl_xor(vLo[nt], 32);
        vHi[nt] += __shfl_xor(vHi[nt], 16); vHi[nt] += __shfl_xor(vHi[nt], 32);
      }
      if (quad == 0) {
        const int gl = gLo - g0;
#pragma unroll
        for (int nt = 0; nt < 4; ++nt) {
          atomicAdd(&gsum[gl * 64 + nt * 16 + col], vLo[nt]);
          atomicAdd(&gsum[(gl + 1) * 64 + nt * 16 + col], vHi[nt]);
        }
      }
    } else {
      // relu -> bf16 -> zt repack, then coalesced 32B/lane store
#pragma unroll
      for (int nt = 0; nt < 4; ++nt) {
        int oblk = nt * 2 + (col >> 3);
#pragma unroll
        for (int r = 0; r < 4; ++r) {
          int rw = quad * 4 + r;
          float v = fmaxf(acc2[nt][r] + bb_n[nt], 0.0f);
          zt[wbase + rw * 64 + (((oblk ^ (rw & 7)) << 3) | (col & 7))] = f2bf_bits(v);
          scol[nt] += v; qcol[nt] += v * v;
        }
      }
      const int R = lane >> 2, sp = lane & 3;
      short8 w0 = *(const short8*)&zt[wbase + R * 64 + (((sp * 2) ^ (R & 7)) << 3)];
      short8 w1 = *(const short8*)&zt[wbase + R * 64 + (((sp * 2 + 1) ^ (R & 7)) << 3)];
      ushort_t* dst = routb + (size_t)(tile + R) * 64 + sp * 16;
      *(short8*)dst = w0;
      *(short8*)(dst + 8) = w1;
    }
  }

#pragma unroll
  for (int nt = 0; nt < 4; ++nt) {
    float s = scol[nt], q = qcol[nt];
    s += __shfl_xor(s, 16); s += __shfl_xor(s, 32);
    q += __shfl_xor(q, 16); q += __shfl_xor(q, 32);
    if (quad == 0) {
      red[wave * 128 + nt * 16 + col] = s;
      red[wave * 128 + 64 + nt * 16 + col] = q;
    }
  }
  __syncthreads();
  if (tid < 128)
    part[blockIdx.x * 128 + tid] =
        red[tid] + red[128 + tid] + red[256 + tid] + red[384 + tid];

  if (GS) {
    // flush per-block graph sums (boundary graphs merged via atomics)
    for (int i = tid; i < 384; i += 256) {
      int g = g0 + (i >> 6);
      float v = gsum[i];
      if (g < NG && v != 0.0f) atomicAdd(&gsum_g[(size_t)g * 64 + (i & 63)], v);
    }
  }
}

// ---------------------------------------------------------------- BN reduce+finalize (merged)
// grid = 64; block c reduces sum (col c) and sumsq (col 64+c), writes ss.
__global__ __launch_bounds__(256) void reduce_finalize(
    const float* __restrict__ part, const float* __restrict__ gma,
    const float* __restrict__ bta, float* __restrict__ ss) {
  __shared__ double sh[512];
  const int c = blockIdx.x, tid = threadIdx.x;
  double a = 0.0, b = 0.0;
  for (int blk = tid; blk < NPBLK; blk += 256) {
    a += (double)part[blk * 128 + c];
    b += (double)part[blk * 128 + 64 + c];
  }
  sh[tid] = a; sh[256 + tid] = b;
  __syncthreads();
  for (int s = 128; s; s >>= 1) {
    if (tid < s) { sh[tid] += sh[tid + s]; sh[256 + tid] += sh[256 + tid + s]; }
    __syncthreads();
  }
  if (tid == 0) {
    double mean = sh[0] / (double)NN;
    double var = sh[256] / (double)NN - mean * mean;
    double sc = (double)gma[c] / sqrt(var + 1e-5);
    ss[c] = (float)sc;
    ss[64 + c] = (float)((double)bta[c] - mean * sc);
  }
}

// ---------------------------------------------------------------- final fc from per-graph sums
// pooled = sc3 * S_g + 62*sf3 ; out = pooled @ Wfc + bfc. 4 graphs/block.
__global__ __launch_bounds__(256) void fc_out(
    const float* __restrict__ gsum_g, const float* __restrict__ ss,
    const float* __restrict__ wfc, const float* __restrict__ bfc,
    float* __restrict__ out) {
  const int lane = threadIdx.x & 63;
  const int g = blockIdx.x * 4 + (threadIdx.x >> 6);
  const int c = lane;
  float s = gsum_g[(size_t)g * 64 + c];
  float pooled = fmaf(ss[c], s, (float)NPG * ss[64 + c]);
#pragma unroll
  for (int j = 0; j < 3; ++j) {
    float v = pooled * wfc[c * 3 + j];
    for (int m = 32; m; m >>= 1) v += __shfl_xor(v, m);
    if (c == 0) out[g * 3 + j] = v + bfc[j];
  }
}

// ---------------------------------------------------------------- launch
extern "C" void kernel_launch(void* const* d_in, const int* in_sizes, int n_in,
                              void* d_out, int out_size, void* d_ws, size_t ws_size,
                              hipStream_t stream) {
  const float* x    = (const float*)d_in[0];
  const int*   srcE = (const int*)d_in[1];
  const int*   dstE = (const int*)d_in[2];
  const float* W1a = (const float*)d_in[4],  *b1a = (const float*)d_in[5];
  const float* W1b = (const float*)d_in[6],  *b1b = (const float*)d_in[7];
  const float* g1  = (const float*)d_in[8],  *be1 = (const float*)d_in[9];
  const float* W2a = (const float*)d_in[10], *b2a = (const float*)d_in[11];
  const float* W2b = (const float*)d_in[12], *b2b = (const float*)d_in[13];
  const float* g2  = (const float*)d_in[14], *be2 = (const float*)d_in[15];
  const float* W3a = (const float*)d_in[16], *b3a = (const float*)d_in[17];
  const float* W3b = (const float*)d_in[18], *b3b = (const float*)d_in[19];
  const float* g3  = (const float*)d_in[20], *be3 = (const float*)d_in[21];
  const float* Wfc = (const float*)d_in[22], *bfc = (const float*)d_in[23];

  float* ws = (float*)d_ws;
  ushort_t* Rb     = (ushort_t*)(ws + OFF_R);    // bf16 rows + sentinel (L1 out)
  float*    GSUM   = ws + OFF_GSUM;              // per-graph sums (L3 out)
  float*    PART   = ws + OFF_PART;
  ushort_t* Ab     = (ushort_t*)(ws + OFF_AGGBF);// bf16 rows + sentinel (L2 out)
  void*     T1     = (void*)(ws + OFF_AGGBF);    // alias: L1 gather out (fp32 t)
  uint2*    RECS   = (uint2*)(ws + OFF_AGGBF);   // alias: dead before gather1
  int*      CSR    = (int*)(ws + OFF_CSR);
  int2*     OC     = (int2*)(ws + OFF_OC);
  int*      BCUR   = (int*)(ws + OFF_BCUR);
  ushort_t* WTB    = (ushort_t*)(ws + OFF_WTB);
  float*    SS     = ws + OFF_SS;

  // weights + BCUR + sentinels + GSUM zero in one dispatch
  prep_weights<<<519, 256, 0, stream>>>(W1a, W1b, W2a, W2b, W3a, W3b, WTB, BCUR,
                                        (unsigned*)(Rb + (size_t)NN * 64),
                                        (unsigned*)(Ab + (size_t)NN * 64),
                                        GSUM);

  // ---- CSR build (bucket sort, LDS cursors, padded to 8 with sentinel NN)
  p3_bin<<<P3BLK, 256, 0, stream>>>(srcE, dstE, BCUR, RECS);
  p4_build<<<NB, 1024, 0, stream>>>(RECS, BCUR, CSR, OC);

  // ---- layer 1: gather(x) -> T1(fp32 t), MLP -> Rb(bf16)
  gather1<<<NN / 256, 256, 0, stream>>>((const float4*)x, CSR, OC, (float4*)T1);
  mlp_l1<<<NPBLK, 256, 0, stream>>>((const float4*)T1, WTB + WB_W1A, b1a,
                                    WTB + WB_W1B, b1b, Rb, PART);
  reduce_finalize<<<64, 256, 0, stream>>>(PART, g1, be1, SS + 0);

  // ---- layer 2 (fused): read Rb (random), write Ab (bf16, coalesced)
  mlp_fused<false><<<NPBLK, 256, 0, stream>>>(Rb, CSR, OC, SS + 0,
                                              WTB + WB_W2A, b2a,
                                              WTB + WB_W2B, b2b,
                                              Ab, nullptr, PART);
  reduce_finalize<<<64, 256, 0, stream>>>(PART, g2, be2, SS + 128);

  // ---- layer 3 (fused): read Ab (random), emit per-graph sums (no row out)
  mlp_fused<true><<<NPBLK, 256, 0, stream>>>(Ab, CSR, OC, SS + 128,
                                             WTB + WB_W3A, b3a,
                                             WTB + WB_W3B, b3b,
                                             nullptr, GSUM, PART);
  reduce_finalize<<<64, 256, 0, stream>>>(PART, g3, be3, SS + 256);

  // ---- classifier from per-graph sums
  fc_out<<<NG / 4, 256, 0, stream>>>(GSUM, SS + 256, Wfc, bfc, (float*)d_out);
}

// Round 9
// 570.171 us; speedup vs baseline: 1.1339x; 1.1302x over previous
//
#include <hip/hip_runtime.h>
#include <hip/hip_bf16.h>

// Problem constants (fixed by the reference)
#define NN   507904          // nodes = 8192*62
#define NE   4063232         // edges = NN*8
#define NG   8192            // graphs
#define NPG  62              // nodes per graph
#define NPBLK 1984           // NN/256 (mlp grid; 256 rows/block, 4 iters)

// Bucket sort parameters
#define NB    248            // buckets = NN/2048 (exact)
#define BRNG  2048           // nodes per bucket (bucket = dst>>11)
#define BCAP  17152          // bucket record capacity (mean 16384, +6 sigma)
#define PBCAP 31744          // padded csr capacity/bucket (8-aligned)
#define P3BLK 992            // NE/4096 (exact)
#define CSRSZ (NB * PBCAP)   // 7,872,512 ints

// ---------------------------------------------------------------- ws layout (4B units)
// OFF_R region (NN*64 units) is multiplexed:
//   [0, NN*32)              Rb bf16 rows (L1 out)
//   [NN*32, +32)            Rb sentinel row
//   OFF_GSUM (NG*64)        per-graph fp32 sums (L3 out)
//   OFF_PART (NPBLK*128)    BN partials
#define OFF_R     0
#define OFF_GSUM  (OFF_R + NN * 32 + 64)
#define OFF_PART  (OFF_GSUM + NG * 64)
#define OFF_AGGBF (OFF_R + NN * 64)          // Ab bf16 rows (+sentinel) | alias: RECS / L1 t
#define OFF_CSR   (OFF_AGGBF + NN * 32 + 32) // CSRSZ ints (padded CSR)
#define OFF_OC    (OFF_CSR + CSRSZ)          // NN int2 (off,deg)
#define OFF_BCUR  (OFF_OC + 2 * NN)          // 256 ints
#define OFF_WTB   (OFF_BCUR + 256)           // bf16 weights: 22528 ushort = 11264 units
#define OFF_SS    (OFF_WTB + 11264)          // 3 x (scale[64], shift[64])

// bf16 weight offsets (ushort units)
#define WB_W1B 0
#define WB_W2A 4096
#define WB_W2B 8192
#define WB_W3A 12288
#define WB_W3B 16384
#define WB_W1A 20480         // 64 x 32, zero-padded K (only k<4 nonzero)

typedef __attribute__((ext_vector_type(8))) short short8;
typedef __attribute__((ext_vector_type(4))) float f32x4;
typedef unsigned short ushort_t;

__device__ __forceinline__ ushort_t f2bf_bits(float f) {
  union { float f; unsigned u; } x; x.f = f;
  unsigned r = x.u + 0x7FFF + ((x.u >> 16) & 1);
  return (ushort_t)(r >> 16);
}
__device__ __forceinline__ float bfu(ushort_t u) {
  union { unsigned i; float f; } x; x.i = ((unsigned)u) << 16; return x.f;
}

// ---------------------------------------------------------------- weight prep + zero-inits
__global__ __launch_bounds__(256) void prep_weights(
    const float* __restrict__ w1a, const float* __restrict__ w1b,
    const float* __restrict__ w2a, const float* __restrict__ w2b,
    const float* __restrict__ w3a, const float* __restrict__ w3b,
    ushort_t* __restrict__ wtb, int* __restrict__ bcur,
    unsigned* __restrict__ sent1, unsigned* __restrict__ sent2,
    float* __restrict__ gsum) {
  int b = blockIdx.x, tid = threadIdx.x;
  if (b == 0) {
    // W1a [4][64] -> bf16 [n][32], zero-padded K (k<4 nonzero)
    ushort_t* d = wtb + WB_W1A;
    for (int i = tid; i < 2048; i += 256) {
      int n = i >> 5, k = i & 31;
      d[i] = (k < 4) ? f2bf_bits(w1a[k * 64 + n]) : (ushort_t)0;
    }
  } else if (b == 6) {
    bcur[tid] = 0;                       // 256 ints
    if (tid < 32) { sent1[tid] = 0; sent2[tid] = 0; }   // sentinel rows
  } else if (b >= 7) {
    // zero GSUM: 512 blocks x 1024 floats = NG*64
    float* g = gsum + (size_t)(b - 7) * 1024;
#pragma unroll
    for (int k = 0; k < 4; ++k) g[k * 256 + tid] = 0.0f;
  } else {
    const float* s; ushort_t* d;
    switch (b) {
      case 1: s = w1b; d = wtb + WB_W1B; break;
      case 2: s = w2a; d = wtb + WB_W2A; break;
      case 3: s = w2b; d = wtb + WB_W2B; break;
      case 4: s = w3a; d = wtb + WB_W3A; break;
      default: s = w3b; d = wtb + WB_W3B; break;
    }
    for (int i = tid; i < 4096; i += 256) {
      int k = i >> 6, n = i & 63;              // src [k][n]
      d[n * 64 + k] = f2bf_bits(s[i]);         // dst [n][k]
    }
  }
}

// ---------------------------------------------------------------- CSR build: phase 1 (R6-proven)
__global__ __launch_bounds__(256) void p3_bin(
    const int* __restrict__ src, const int* __restrict__ dst,
    int* __restrict__ bcur, uint2* __restrict__ recs) {
  __shared__ int histo[256];
  __shared__ int scan_s[256];
  __shared__ int base_s[256];
  __shared__ int cur_s[256];
  __shared__ uint2 buf[4096];
  const int tid = threadIdx.x;
  const int e0 = blockIdx.x * 4096;

  histo[tid] = 0;
  __syncthreads();

  int d_[16], s_[16];
#pragma unroll
  for (int k = 0; k < 16; ++k) {
    int e = e0 + k * 256 + tid;
    d_[k] = dst[e]; s_[k] = src[e];
    atomicAdd(&histo[d_[k] >> 11], 1);
  }
  __syncthreads();

  int v = histo[tid];
  scan_s[tid] = v; __syncthreads();
  for (int s = 1; s < 256; s <<= 1) {
    int add = (tid >= s) ? scan_s[tid - s] : 0;
    __syncthreads();
    scan_s[tid] += add;
    __syncthreads();
  }
  int excl = scan_s[tid] - v;
  if (tid < NB) base_s[tid] = atomicAdd(&bcur[tid], v);
  cur_s[tid] = excl;
  histo[tid] = excl;
  __syncthreads();

#pragma unroll
  for (int k = 0; k < 16; ++k) {
    int b = d_[k] >> 11;
    int p = atomicAdd(&cur_s[b], 1);
    uint2 r; r.x = (unsigned)d_[k]; r.y = (unsigned)s_[k];
    buf[p] = r;
  }
  __syncthreads();

  for (int i = tid; i < 4096; i += 256) {
    uint2 r = buf[i];
    int b = (int)(r.x >> 11);
    int g = base_s[b] + (i - histo[b]);
    if (g < BCAP) recs[(size_t)b * BCAP + g] = r;
  }
}

// ---------------------------------------------------------------- CSR build: phase 2 (R6-proven, LDS cursors)
__global__ __launch_bounds__(1024) void p4_build(
    const uint2* __restrict__ recs, const int* __restrict__ bcur,
    int* __restrict__ csr, int2* __restrict__ oc) {
  __shared__ int lcnt[2048];
  __shared__ int pscan[1024];
  __shared__ int sstart[2048];
  __shared__ int scur[2048];
  const int b = blockIdx.x, tid = threadIdx.x;
  int m = bcur[b]; if (m > BCAP) m = BCAP;
  const int cbase = b * PBCAP;
  const int nbase = b << 11;
  const uint2* rp = recs + (size_t)b * BCAP;

  lcnt[tid] = 0; lcnt[1024 + tid] = 0;
  __syncthreads();
  for (int i = tid; i < m; i += 1024)
    atomicAdd(&lcnt[rp[i].x & (BRNG - 1)], 1);
  __syncthreads();

  int a0 = lcnt[2 * tid], a1 = lcnt[2 * tid + 1];
  int p0 = (a0 + 7) & ~7, p1 = (a1 + 7) & ~7;
  int ps = p0 + p1;
  pscan[tid] = ps; __syncthreads();
  for (int s = 1; s < 1024; s <<= 1) {
    int add = (tid >= s) ? pscan[tid - s] : 0;
    __syncthreads();
    pscan[tid] += add;
    __syncthreads();
  }
  int e0 = pscan[tid] - ps;
  sstart[2 * tid] = e0;          scur[2 * tid] = e0;
  sstart[2 * tid + 1] = e0 + p0; scur[2 * tid + 1] = e0 + p0;
  __syncthreads();

  // packed (off,deg) records
  {
    int2 r0; r0.x = cbase + sstart[tid];        r0.y = lcnt[tid];
    int2 r1; r1.x = cbase + sstart[1024 + tid]; r1.y = lcnt[1024 + tid];
    oc[nbase + tid] = r0;
    oc[nbase + 1024 + tid] = r1;
  }
  __syncthreads();

  for (int i = tid; i < m; i += 1024) {
    uint2 r = rp[i];
    int p = atomicAdd(&scur[r.x & (BRNG - 1)], 1);
    csr[cbase + p] = (int)r.y;
  }
  __syncthreads();

#pragma unroll
  for (int k = 0; k < 2; ++k) {
    int i = k * 1024 + tid;
    int st = sstart[i], d = lcnt[i], p = (d + 7) & ~7;
    for (int q = d; q < p; ++q) csr[cbase + st + q] = NN;   // sentinel
  }
}

// ---------------------------------------------------------------- gather L1 (C=4)
__global__ __launch_bounds__(256) void gather1(
    const float4* __restrict__ x, const int* __restrict__ csr,
    const int2* __restrict__ oc, float4* __restrict__ tout) {
  int n = blockIdx.x * 256 + threadIdx.x;
  float4 a = x[n];
  int2 oc_ = oc[n];
  int off = oc_.x, deg = oc_.y;
  const int* cp = csr + off;
  int j = 0;
  for (; j + 4 <= deg; j += 4) {
    int s0 = cp[j], s1 = cp[j + 1], s2 = cp[j + 2], s3 = cp[j + 3];
    float4 v0 = x[s0], v1 = x[s1], v2 = x[s2], v3 = x[s3];
    a.x += v0.x + v1.x + v2.x + v3.x;
    a.y += v0.y + v1.y + v2.y + v3.y;
    a.z += v0.z + v1.z + v2.z + v3.z;
    a.w += v0.w + v1.w + v2.w + v3.w;
  }
  for (; j < deg; ++j) {
    float4 v = x[cp[j]];
    a.x += v.x; a.y += v.y; a.z += v.z; a.w += v.w;
  }
  tout[n] = a;
}

// ---------------------------------------------------------------- MFMA MLP layer 1 (fp32 t in, bf16 out)
// 256 rows/block, 4 iters, grid 1984. Coalesced C-write via zt repack.
__global__ __launch_bounds__(256) void mlp_l1(
    const float4* __restrict__ tin,
    const ushort_t* __restrict__ WaTb,   // bf16 [n][32], zero-padded K
    const float* __restrict__ ba,
    const ushort_t* __restrict__ WbTb,   // bf16 [n][64]
    const float* __restrict__ bb,
    ushort_t* __restrict__ routb,
    float* __restrict__ part) {
  __shared__ __align__(16) ushort_t zt[4096];
  __shared__ float red[512];
  const int tid = threadIdx.x;
  const int wave = tid >> 6, lane = tid & 63;
  const int col = lane & 15, quad = lane >> 4;

  short8 bWa1[4], bWb[2][4];
#pragma unroll
  for (int nt = 0; nt < 4; ++nt) {
    bWa1[nt] = *(const short8*)(WaTb + (nt * 16 + col) * 32 + quad * 8);
#pragma unroll
    for (int k0 = 0; k0 < 2; ++k0)
      bWb[k0][nt] = *(const short8*)(WbTb + (nt * 16 + col) * 64 + k0 * 32 + quad * 8);
  }
  float ba_n[4], bb_n[4];
#pragma unroll
  for (int nt = 0; nt < 4; ++nt) {
    ba_n[nt] = ba[nt * 16 + col];
    bb_n[nt] = bb[nt * 16 + col];
  }

  const int wbase = wave * 1024;
  float scol[4] = {0, 0, 0, 0}, qcol[4] = {0, 0, 0, 0};

  for (int it = 0; it < 4; ++it) {
    const int tile = blockIdx.x * 256 + it * 64 + wave * 16;

    f32x4 acc1[4];
#pragma unroll
    for (int nt = 0; nt < 4; ++nt) acc1[nt] = (f32x4){0.f, 0.f, 0.f, 0.f};

    // A-frag: m=col, k=quad*8+j; real data only k<4
    float4 t4 = tin[tile + col];
    short8 az = {0, 0, 0, 0, 0, 0, 0, 0};
    if (quad == 0) {
      az[0] = (short)f2bf_bits(t4.x);
      az[1] = (short)f2bf_bits(t4.y);
      az[2] = (short)f2bf_bits(t4.z);
      az[3] = (short)f2bf_bits(t4.w);
    }
#pragma unroll
    for (int nt = 0; nt < 4; ++nt)
      acc1[nt] = __builtin_amdgcn_mfma_f32_16x16x32_bf16(az, bWa1[nt], acc1[nt], 0, 0, 0);

    // relu -> bf16 -> wave-private swizzled LDS (C-layout write, A-layout read)
#pragma unroll
    for (int nt = 0; nt < 4; ++nt) {
      int oblk = nt * 2 + (col >> 3);
#pragma unroll
      for (int r = 0; r < 4; ++r) {
        int row = quad * 4 + r;
        float z = fmaxf(acc1[nt][r] + ba_n[nt], 0.0f);
        zt[wbase + row * 64 + (((oblk ^ (row & 7)) << 3) | (col & 7))] = f2bf_bits(z);
      }
    }
    short8 az0 = *(const short8*)&zt[wbase + col * 64 + ((quad ^ (col & 7)) << 3)];
    short8 az1 = *(const short8*)&zt[wbase + col * 64 + (((4 + quad) ^ (col & 7)) << 3)];

    f32x4 acc2[4];
#pragma unroll
    for (int nt = 0; nt < 4; ++nt) acc2[nt] = (f32x4){0.f, 0.f, 0.f, 0.f};
#pragma unroll
    for (int nt = 0; nt < 4; ++nt) {
      acc2[nt] = __builtin_amdgcn_mfma_f32_16x16x32_bf16(az0, bWb[0][nt], acc2[nt], 0, 0, 0);
      acc2[nt] = __builtin_amdgcn_mfma_f32_16x16x32_bf16(az1, bWb[1][nt], acc2[nt], 0, 0, 0);
    }
    // relu -> bf16 -> zt repack (same swizzle), then coalesced 32B/lane store
#pragma unroll
    for (int nt = 0; nt < 4; ++nt) {
      int oblk = nt * 2 + (col >> 3);
#pragma unroll
      for (int r = 0; r < 4; ++r) {
        int rw = quad * 4 + r;
        float v = fmaxf(acc2[nt][r] + bb_n[nt], 0.0f);
        zt[wbase + rw * 64 + (((oblk ^ (rw & 7)) << 3) | (col & 7))] = f2bf_bits(v);
        scol[nt] += v; qcol[nt] += v * v;
      }
    }
    {
      const int R = lane >> 2, sp = lane & 3;
      short8 w0 = *(const short8*)&zt[wbase + R * 64 + (((sp * 2) ^ (R & 7)) << 3)];
      short8 w1 = *(const short8*)&zt[wbase + R * 64 + (((sp * 2 + 1) ^ (R & 7)) << 3)];
      ushort_t* dst = routb + (size_t)(tile + R) * 64 + sp * 16;
      *(short8*)dst = w0;
      *(short8*)(dst + 8) = w1;
    }
  }

#pragma unroll
  for (int nt = 0; nt < 4; ++nt) {
    float s = scol[nt], q = qcol[nt];
    s += __shfl_xor(s, 16); s += __shfl_xor(s, 32);
    q += __shfl_xor(q, 16); q += __shfl_xor(q, 32);
    if (quad == 0) {
      red[wave * 128 + nt * 16 + col] = s;
      red[wave * 128 + 64 + nt * 16 + col] = q;
    }
  }
  __syncthreads();
  if (tid < 128)
    part[blockIdx.x * 128 + tid] =
        red[tid] + red[128 + tid] + red[256 + tid] + red[384 + tid];
}

// ---------------------------------------------------------------- FUSED gather + MFMA MLP (L2/L3)
// Register-resident weights (R5-proven occupancy point: ~124 VGPR, no
// forced launch_bounds). GS=false (L2): bf16 row out via zt repack.
// GS=true (L3): segmented register reduction (wave's 16 rows span <=2
// graphs) + 8 conflict-free LDS atomics/iter + one global flush.
template <bool GS>
__global__ __launch_bounds__(256) void mlp_fused(
    const ushort_t* __restrict__ h,
    const int* __restrict__ csr, const int2* __restrict__ oc,
    const float* __restrict__ ss,
    const ushort_t* __restrict__ WaTb,   // bf16 [n][64]
    const float* __restrict__ ba,
    const ushort_t* __restrict__ WbTb,   // bf16 [n][64]
    const float* __restrict__ bb,
    ushort_t* __restrict__ routb, float* __restrict__ gsum_g,
    float* __restrict__ part) {
  __shared__ __align__(16) ushort_t zt[4096];
  __shared__ float red[512];
  __shared__ float ssl[128];
  __shared__ float gsum[GS ? 384 : 1];   // 6 graphs x 64 ch
  const int tid = threadIdx.x;
  const int wave = tid >> 6, lane = tid & 63;
  const int col = lane & 15, quad = lane >> 4;
  if (tid < 128) ssl[tid] = ss[tid];
  const int g0 = (blockIdx.x * 256) / 62;   // first graph touched by block
  if (GS) {
    for (int i = tid; i < 384; i += 256) gsum[i] = 0.0f;
  }

  short8 bWa[2][4], bWb[2][4];
#pragma unroll
  for (int nt = 0; nt < 4; ++nt) {
#pragma unroll
    for (int k0 = 0; k0 < 2; ++k0) {
      bWa[k0][nt] = *(const short8*)(WaTb + (nt * 16 + col) * 64 + k0 * 32 + quad * 8);
      bWb[k0][nt] = *(const short8*)(WbTb + (nt * 16 + col) * 64 + k0 * 32 + quad * 8);
    }
  }
  float ba_n[4], bb_n[4];
#pragma unroll
  for (int nt = 0; nt < 4; ++nt) {
    ba_n[nt] = ba[nt * 16 + col];
    bb_n[nt] = bb[nt * 16 + col];
  }
  __syncthreads();   // ssl (+gsum) ready

  const float* scA = ssl + quad * 8;        // sc channels kA = quad*8+e
  const float* scB = ssl + 32 + quad * 8;   // sc channels kB = 32+quad*8+e
  const float* sfA = ssl + 64 + quad * 8;
  const float* sfB = ssl + 96 + quad * 8;

  const int wbase = wave * 1024;
  float scol[4] = {0, 0, 0, 0}, qcol[4] = {0, 0, 0, 0};

  for (int it = 0; it < 4; ++it) {
    const int tile = blockIdx.x * 256 + it * 64 + wave * 16;
    const int row = tile + col;
    const int2 o = oc[row];

    // self row (eps=0 GIN)
    const ushort_t* hp = h + (size_t)(unsigned)row * 64u + quad * 8;
    short8 sl0 = *(const short8*)hp;
    short8 sl1 = *(const short8*)(hp + 32);
    float accA[8], accB[8];
#pragma unroll
    for (int e = 0; e < 8; ++e) {
      accA[e] = bfu((ushort_t)sl0[e]);
      accB[e] = bfu((ushort_t)sl1[e]);
    }

    const int chunks = (o.y + 7) >> 3;
    for (int c = 0; c < chunks; ++c) {
      const int* cp = csr + o.x + (c << 3);
      int4 i0 = *(const int4*)cp;
      int4 i1 = *(const int4*)(cp + 4);
      int idx[8] = {i0.x, i0.y, i0.z, i0.w, i1.x, i1.y, i1.z, i1.w};
#pragma unroll
      for (int j = 0; j < 8; ++j) {
        const ushort_t* p = h + (size_t)(unsigned)idx[j] * 64u + quad * 8;
        short8 l0 = *(const short8*)p;
        short8 l1 = *(const short8*)(p + 32);
#pragma unroll
        for (int e = 0; e < 8; ++e) {
          accA[e] += bfu((ushort_t)l0[e]);
          accB[e] += bfu((ushort_t)l1[e]);
        }
      }
    }

    // folded BN of previous layer: t = sc*acc + (deg+1)*sf  (sentinels add 0)
    const float m1 = (float)(o.y + 1);
    short8 a0, a1;
#pragma unroll
    for (int e = 0; e < 8; ++e) {
      a0[e] = (short)f2bf_bits(fmaf(scA[e], accA[e], m1 * sfA[e]));
      a1[e] = (short)f2bf_bits(fmaf(scB[e], accB[e], m1 * sfB[e]));
    }

    f32x4 acc1[4];
#pragma unroll
    for (int nt = 0; nt < 4; ++nt) acc1[nt] = (f32x4){0.f, 0.f, 0.f, 0.f};
#pragma unroll
    for (int nt = 0; nt < 4; ++nt) {
      acc1[nt] = __builtin_amdgcn_mfma_f32_16x16x32_bf16(a0, bWa[0][nt], acc1[nt], 0, 0, 0);
      acc1[nt] = __builtin_amdgcn_mfma_f32_16x16x32_bf16(a1, bWa[1][nt], acc1[nt], 0, 0, 0);
    }

    // relu -> bf16 -> wave-private swizzled LDS (C-layout write, A-layout read)
#pragma unroll
    for (int nt = 0; nt < 4; ++nt) {
      int oblk = nt * 2 + (col >> 3);
#pragma unroll
      for (int r = 0; r < 4; ++r) {
        int rw = quad * 4 + r;
        float z = fmaxf(acc1[nt][r] + ba_n[nt], 0.0f);
        zt[wbase + rw * 64 + (((oblk ^ (rw & 7)) << 3) | (col & 7))] = f2bf_bits(z);
      }
    }
    short8 az0 = *(const short8*)&zt[wbase + col * 64 + ((quad ^ (col & 7)) << 3)];
    short8 az1 = *(const short8*)&zt[wbase + col * 64 + (((4 + quad) ^ (col & 7)) << 3)];

    f32x4 acc2[4];
#pragma unroll
    for (int nt = 0; nt < 4; ++nt) acc2[nt] = (f32x4){0.f, 0.f, 0.f, 0.f};
#pragma unroll
    for (int nt = 0; nt < 4; ++nt) {
      acc2[nt] = __builtin_amdgcn_mfma_f32_16x16x32_bf16(az0, bWb[0][nt], acc2[nt], 0, 0, 0);
      acc2[nt] = __builtin_amdgcn_mfma_f32_16x16x32_bf16(az1, bWb[1][nt], acc2[nt], 0, 0, 0);
    }

    if (GS) {
      // segmented per-graph reduction: a wave's 16 rows span <=2 graphs.
      const int gLo = tile / 62;
      const int rEnd = (gLo + 1) * 62;
      float vLo[4], vHi[4];
#pragma unroll
      for (int nt = 0; nt < 4; ++nt) { vLo[nt] = 0.f; vHi[nt] = 0.f; }
#pragma unroll
      for (int nt = 0; nt < 4; ++nt) {
#pragma unroll
        for (int r = 0; r < 4; ++r) {
          int rw = tile + quad * 4 + r;
          float v = fmaxf(acc2[nt][r] + bb_n[nt], 0.0f);
          scol[nt] += v; qcol[nt] += v * v;
          if (rw < rEnd) vLo[nt] += v; else vHi[nt] += v;
        }
      }
#pragma unroll
      for (int nt = 0; nt < 4; ++nt) {
        vLo[nt] += __shfl_xor(vLo[nt], 16); vLo[nt] += __shfl_xor(vLo[nt], 32);
        vHi[nt] += __shfl_xor(vHi[nt], 16); vHi[nt] += __shfl_xor(vHi[nt], 32);
      }
      if (quad == 0) {
        const int gl = gLo - g0;
#pragma unroll
        for (int nt = 0; nt < 4; ++nt) {
          atomicAdd(&gsum[gl * 64 + nt * 16 + col], vLo[nt]);
          atomicAdd(&gsum[(gl + 1) * 64 + nt * 16 + col], vHi[nt]);
        }
      }
    } else {
      // relu -> bf16 -> zt repack, then coalesced 32B/lane store
#pragma unroll
      for (int nt = 0; nt < 4; ++nt) {
        int oblk = nt * 2 + (col >> 3);
#pragma unroll
        for (int r = 0; r < 4; ++r) {
          int rw = quad * 4 + r;
          float v = fmaxf(acc2[nt][r] + bb_n[nt], 0.0f);
          zt[wbase + rw * 64 + (((oblk ^ (rw & 7)) << 3) | (col & 7))] = f2bf_bits(v);
          scol[nt] += v; qcol[nt] += v * v;
        }
      }
      const int R = lane >> 2, sp = lane & 3;
      short8 w0 = *(const short8*)&zt[wbase + R * 64 + (((sp * 2) ^ (R & 7)) << 3)];
      short8 w1 = *(const short8*)&zt[wbase + R * 64 + (((sp * 2 + 1) ^ (R & 7)) << 3)];
      ushort_t* dst = routb + (size_t)(tile + R) * 64 + sp * 16;
      *(short8*)dst = w0;
      *(short8*)(dst + 8) = w1;
    }
  }

#pragma unroll
  for (int nt = 0; nt < 4; ++nt) {
    float s = scol[nt], q = qcol[nt];
    s += __shfl_xor(s, 16); s += __shfl_xor(s, 32);
    q += __shfl_xor(q, 16); q += __shfl_xor(q, 32);
    if (quad == 0) {
      red[wave * 128 + nt * 16 + col] = s;
      red[wave * 128 + 64 + nt * 16 + col] = q;
    }
  }
  __syncthreads();
  if (tid < 128)
    part[blockIdx.x * 128 + tid] =
        red[tid] + red[128 + tid] + red[256 + tid] + red[384 + tid];

  if (GS) {
    // flush per-block graph sums (boundary graphs merged via atomics)
    for (int i = tid; i < 384; i += 256) {
      int g = g0 + (i >> 6);
      float v = gsum[i];
      if (g < NG && v != 0.0f) atomicAdd(&gsum_g[(size_t)g * 64 + (i & 63)], v);
    }
  }
}

// ---------------------------------------------------------------- BN reduce+finalize (merged)
// grid = 64; block c reduces sum (col c) and sumsq (col 64+c), writes ss.
__global__ __launch_bounds__(256) void reduce_finalize(
    const float* __restrict__ part, const float* __restrict__ gma,
    const float* __restrict__ bta, float* __restrict__ ss) {
  __shared__ double sh[512];
  const int c = blockIdx.x, tid = threadIdx.x;
  double a = 0.0, b = 0.0;
  for (int blk = tid; blk < NPBLK; blk += 256) {
    a += (double)part[blk * 128 + c];
    b += (double)part[blk * 128 + 64 + c];
  }
  sh[tid] = a; sh[256 + tid] = b;
  __syncthreads();
  for (int s = 128; s; s >>= 1) {
    if (tid < s) { sh[tid] += sh[tid + s]; sh[256 + tid] += sh[256 + tid + s]; }
    __syncthreads();
  }
  if (tid == 0) {
    double mean = sh[0] / (double)NN;
    double var = sh[256] / (double)NN - mean * mean;
    double sc = (double)gma[c] / sqrt(var + 1e-5);
    ss[c] = (float)sc;
    ss[64 + c] = (float)((double)bta[c] - mean * sc);
  }
}

// ---------------------------------------------------------------- final fc from per-graph sums
// pooled = sc3 * S_g + 62*sf3 ; out = pooled @ Wfc + bfc. 4 graphs/block.
__global__ __launch_bounds__(256) void fc_out(
    const float* __restrict__ gsum_g, const float* __restrict__ ss,
    const float* __restrict__ wfc, const float* __restrict__ bfc,
    float* __restrict__ out) {
  const int lane = threadIdx.x & 63;
  const int g = blockIdx.x * 4 + (threadIdx.x >> 6);
  const int c = lane;
  float s = gsum_g[(size_t)g * 64 + c];
  float pooled = fmaf(ss[c], s, (float)NPG * ss[64 + c]);
#pragma unroll
  for (int j = 0; j < 3; ++j) {
    float v = pooled * wfc[c * 3 + j];
    for (int m = 32; m; m >>= 1) v += __shfl_xor(v, m);
    if (c == 0) out[g * 3 + j] = v + bfc[j];
  }
}

// ---------------------------------------------------------------- launch
extern "C" void kernel_launch(void* const* d_in, const int* in_sizes, int n_in,
                              void* d_out, int out_size, void* d_ws, size_t ws_size,
                              hipStream_t stream) {
  const float* x    = (const float*)d_in[0];
  const int*   srcE = (const int*)d_in[1];
  const int*   dstE = (const int*)d_in[2];
  const float* W1a = (const float*)d_in[4],  *b1a = (const float*)d_in[5];
  const float* W1b = (const float*)d_in[6],  *b1b = (const float*)d_in[7];
  const float* g1  = (const float*)d_in[8],  *be1 = (const float*)d_in[9];
  const float* W2a = (const float*)d_in[10], *b2a = (const float*)d_in[11];
  const float* W2b = (const float*)d_in[12], *b2b = (const float*)d_in[13];
  const float* g2  = (const float*)d_in[14], *be2 = (const float*)d_in[15];
  const float* W3a = (const float*)d_in[16], *b3a = (const float*)d_in[17];
  const float* W3b = (const float*)d_in[18], *b3b = (const float*)d_in[19];
  const float* g3  = (const float*)d_in[20], *be3 = (const float*)d_in[21];
  const float* Wfc = (const float*)d_in[22], *bfc = (const float*)d_in[23];

  float* ws = (float*)d_ws;
  ushort_t* Rb     = (ushort_t*)(ws + OFF_R);    // bf16 rows + sentinel (L1 out)
  float*    GSUM   = ws + OFF_GSUM;              // per-graph sums (L3 out)
  float*    PART   = ws + OFF_PART;
  ushort_t* Ab     = (ushort_t*)(ws + OFF_AGGBF);// bf16 rows + sentinel (L2 out)
  void*     T1     = (void*)(ws + OFF_AGGBF);    // alias: L1 gather out (fp32 t)
  uint2*    RECS   = (uint2*)(ws + OFF_AGGBF);   // alias: dead before gather1
  int*      CSR    = (int*)(ws + OFF_CSR);
  int2*     OC     = (int2*)(ws + OFF_OC);
  int*      BCUR   = (int*)(ws + OFF_BCUR);
  ushort_t* WTB    = (ushort_t*)(ws + OFF_WTB);
  float*    SS     = ws + OFF_SS;

  // weights + BCUR + sentinels + GSUM zero in one dispatch
  prep_weights<<<519, 256, 0, stream>>>(W1a, W1b, W2a, W2b, W3a, W3b, WTB, BCUR,
                                        (unsigned*)(Rb + (size_t)NN * 64),
                                        (unsigned*)(Ab + (size_t)NN * 64),
                                        GSUM);

  // ---- CSR build (bucket sort, LDS cursors, padded to 8 with sentinel NN)
  p3_bin<<<P3BLK, 256, 0, stream>>>(srcE, dstE, BCUR, RECS);
  p4_build<<<NB, 1024, 0, stream>>>(RECS, BCUR, CSR, OC);

  // ---- layer 1: gather(x) -> T1(fp32 t), MLP -> Rb(bf16)
  gather1<<<NN / 256, 256, 0, stream>>>((const float4*)x, CSR, OC, (float4*)T1);
  mlp_l1<<<NPBLK, 256, 0, stream>>>((const float4*)T1, WTB + WB_W1A, b1a,
                                    WTB + WB_W1B, b1b, Rb, PART);
  reduce_finalize<<<64, 256, 0, stream>>>(PART, g1, be1, SS + 0);

  // ---- layer 2 (fused): read Rb (random), write Ab (bf16, coalesced)
  mlp_fused<false><<<NPBLK, 256, 0, stream>>>(Rb, CSR, OC, SS + 0,
                                              WTB + WB_W2A, b2a,
                                              WTB + WB_W2B, b2b,
                                              Ab, nullptr, PART);
  reduce_finalize<<<64, 256, 0, stream>>>(PART, g2, be2, SS + 128);

  // ---- layer 3 (fused): read Ab (random), emit per-graph sums (no row out)
  mlp_fused<true><<<NPBLK, 256, 0, stream>>>(Ab, CSR, OC, SS + 128,
                                             WTB + WB_W3A, b3a,
                                             WTB + WB_W3B, b3b,
                                             nullptr, GSUM, PART);
  reduce_finalize<<<64, 256, 0, stream>>>(PART, g3, be3, SS + 256);

  // ---- classifier from per-graph sums
  fc_out<<<NG / 4, 256, 0, stream>>>(GSUM, SS + 256, Wfc, bfc, (float*)d_out);
}

// Round 10
// 539.743 us; speedup vs baseline: 1.1978x; 1.0564x over previous
//
#include <hip/hip_runtime.h>
#include <hip/hip_bf16.h>

// Problem constants (fixed by the reference)
#define NN   507904          // nodes = 8192*62
#define NE   4063232         // edges = NN*8
#define NG   8192            // graphs
#define NPG  62              // nodes per graph
#define NBLKF 992            // NN/512 (mlp grid; 512 rows/block, 8 iters; R5-proven)

// Bucket sort parameters
#define NB    248            // buckets = NN/2048 (exact)
#define BRNG  2048           // nodes per bucket (bucket = dst>>11)
#define BCAP  17152          // bucket record capacity (mean 16384, +6 sigma)
#define PBCAP 31744          // padded csr capacity/bucket (8-aligned)
#define P3BLK 992            // NE/4096 (exact)
#define CSRSZ (NB * PBCAP)   // 7,872,512 ints

// ---------------------------------------------------------------- ws layout (4B units)
// OFF_R region (NN*64 units) is multiplexed:
//   [0, NN*32)              Rb bf16 rows (L1 out)
//   [NN*32, +32)            Rb sentinel row
//   OFF_GSUM (NG*64)        per-graph fp32 sums (L3 out)
//   OFF_PART (NBLKF*128)    BN partials
#define OFF_R     0
#define OFF_GSUM  (OFF_R + NN * 32 + 64)
#define OFF_PART  (OFF_GSUM + NG * 64)
#define OFF_AGGBF (OFF_R + NN * 64)          // Ab bf16 rows (+sentinel) | alias: RECS
#define OFF_CSR   (OFF_AGGBF + NN * 32 + 32) // CSRSZ ints (padded CSR)
#define OFF_OC    (OFF_CSR + CSRSZ)          // NN int2 (off,deg)
#define OFF_BCUR  (OFF_OC + 2 * NN)          // 256 ints
#define OFF_WTB   (OFF_BCUR + 256)           // bf16 weights: 22528 ushort = 11264 units
#define OFF_SS    (OFF_WTB + 11264)          // 3 x (scale[64], shift[64])

// bf16 weight offsets (ushort units)
#define WB_W1B 0
#define WB_W2A 4096
#define WB_W2B 8192
#define WB_W3A 12288
#define WB_W3B 16384
#define WB_W1A 20480         // 64 x 32, zero-padded K (only k<4 nonzero)

typedef __attribute__((ext_vector_type(8))) short short8;
typedef __attribute__((ext_vector_type(4))) float f32x4;
typedef unsigned short ushort_t;

__device__ __forceinline__ ushort_t f2bf_bits(float f) {
  union { float f; unsigned u; } x; x.f = f;
  unsigned r = x.u + 0x7FFF + ((x.u >> 16) & 1);
  return (ushort_t)(r >> 16);
}
__device__ __forceinline__ float bfu(ushort_t u) {
  union { unsigned i; float f; } x; x.i = ((unsigned)u) << 16; return x.f;
}

// ---------------------------------------------------------------- weight prep + zero-inits
__global__ __launch_bounds__(256) void prep_weights(
    const float* __restrict__ w1a, const float* __restrict__ w1b,
    const float* __restrict__ w2a, const float* __restrict__ w2b,
    const float* __restrict__ w3a, const float* __restrict__ w3b,
    ushort_t* __restrict__ wtb, int* __restrict__ bcur,
    unsigned* __restrict__ sent1, unsigned* __restrict__ sent2,
    float* __restrict__ gsum) {
  int b = blockIdx.x, tid = threadIdx.x;
  if (b == 0) {
    // W1a [4][64] -> bf16 [n][32], zero-padded K (k<4 nonzero)
    ushort_t* d = wtb + WB_W1A;
    for (int i = tid; i < 2048; i += 256) {
      int n = i >> 5, k = i & 31;
      d[i] = (k < 4) ? f2bf_bits(w1a[k * 64 + n]) : (ushort_t)0;
    }
  } else if (b == 6) {
    bcur[tid] = 0;                       // 256 ints
    if (tid < 32) { sent1[tid] = 0; sent2[tid] = 0; }   // sentinel rows
  } else if (b >= 7) {
    // zero GSUM: 512 blocks x 1024 floats = NG*64
    float* g = gsum + (size_t)(b - 7) * 1024;
#pragma unroll
    for (int k = 0; k < 4; ++k) g[k * 256 + tid] = 0.0f;
  } else {
    const float* s; ushort_t* d;
    switch (b) {
      case 1: s = w1b; d = wtb + WB_W1B; break;
      case 2: s = w2a; d = wtb + WB_W2A; break;
      case 3: s = w2b; d = wtb + WB_W2B; break;
      case 4: s = w3a; d = wtb + WB_W3A; break;
      default: s = w3b; d = wtb + WB_W3B; break;
    }
    for (int i = tid; i < 4096; i += 256) {
      int k = i >> 6, n = i & 63;              // src [k][n]
      d[n * 64 + k] = f2bf_bits(s[i]);         // dst [n][k]
    }
  }
}

// ---------------------------------------------------------------- CSR build: phase 1 (R6-proven)
__global__ __launch_bounds__(256) void p3_bin(
    const int* __restrict__ src, const int* __restrict__ dst,
    int* __restrict__ bcur, uint2* __restrict__ recs) {
  __shared__ int histo[256];
  __shared__ int scan_s[256];
  __shared__ int base_s[256];
  __shared__ int cur_s[256];
  __shared__ uint2 buf[4096];
  const int tid = threadIdx.x;
  const int e0 = blockIdx.x * 4096;

  histo[tid] = 0;
  __syncthreads();

  int d_[16], s_[16];
#pragma unroll
  for (int k = 0; k < 16; ++k) {
    int e = e0 + k * 256 + tid;
    d_[k] = dst[e]; s_[k] = src[e];
    atomicAdd(&histo[d_[k] >> 11], 1);
  }
  __syncthreads();

  int v = histo[tid];
  scan_s[tid] = v; __syncthreads();
  for (int s = 1; s < 256; s <<= 1) {
    int add = (tid >= s) ? scan_s[tid - s] : 0;
    __syncthreads();
    scan_s[tid] += add;
    __syncthreads();
  }
  int excl = scan_s[tid] - v;
  if (tid < NB) base_s[tid] = atomicAdd(&bcur[tid], v);
  cur_s[tid] = excl;
  histo[tid] = excl;
  __syncthreads();

#pragma unroll
  for (int k = 0; k < 16; ++k) {
    int b = d_[k] >> 11;
    int p = atomicAdd(&cur_s[b], 1);
    uint2 r; r.x = (unsigned)d_[k]; r.y = (unsigned)s_[k];
    buf[p] = r;
  }
  __syncthreads();

  for (int i = tid; i < 4096; i += 256) {
    uint2 r = buf[i];
    int b = (int)(r.x >> 11);
    int g = base_s[b] + (i - histo[b]);
    if (g < BCAP) recs[(size_t)b * BCAP + g] = r;
  }
}

// ---------------------------------------------------------------- CSR build: phase 2 (R6-proven, LDS cursors)
__global__ __launch_bounds__(1024) void p4_build(
    const uint2* __restrict__ recs, const int* __restrict__ bcur,
    int* __restrict__ csr, int2* __restrict__ oc) {
  __shared__ int lcnt[2048];
  __shared__ int pscan[1024];
  __shared__ int sstart[2048];
  __shared__ int scur[2048];
  const int b = blockIdx.x, tid = threadIdx.x;
  int m = bcur[b]; if (m > BCAP) m = BCAP;
  const int cbase = b * PBCAP;
  const int nbase = b << 11;
  const uint2* rp = recs + (size_t)b * BCAP;

  lcnt[tid] = 0; lcnt[1024 + tid] = 0;
  __syncthreads();
  for (int i = tid; i < m; i += 1024)
    atomicAdd(&lcnt[rp[i].x & (BRNG - 1)], 1);
  __syncthreads();

  int a0 = lcnt[2 * tid], a1 = lcnt[2 * tid + 1];
  int p0 = (a0 + 7) & ~7, p1 = (a1 + 7) & ~7;
  int ps = p0 + p1;
  pscan[tid] = ps; __syncthreads();
  for (int s = 1; s < 1024; s <<= 1) {
    int add = (tid >= s) ? pscan[tid - s] : 0;
    __syncthreads();
    pscan[tid] += add;
    __syncthreads();
  }
  int e0 = pscan[tid] - ps;
  sstart[2 * tid] = e0;          scur[2 * tid] = e0;
  sstart[2 * tid + 1] = e0 + p0; scur[2 * tid + 1] = e0 + p0;
  __syncthreads();

  // packed (off,deg) records
  {
    int2 r0; r0.x = cbase + sstart[tid];        r0.y = lcnt[tid];
    int2 r1; r1.x = cbase + sstart[1024 + tid]; r1.y = lcnt[1024 + tid];
    oc[nbase + tid] = r0;
    oc[nbase + 1024 + tid] = r1;
  }
  __syncthreads();

  for (int i = tid; i < m; i += 1024) {
    uint2 r = rp[i];
    int p = atomicAdd(&scur[r.x & (BRNG - 1)], 1);
    csr[cbase + p] = (int)r.y;
  }
  __syncthreads();

#pragma unroll
  for (int k = 0; k < 2; ++k) {
    int i = k * 1024 + tid;
    int st = sstart[i], d = lcnt[i], p = (d + 7) & ~7;
    for (int q = d; q < p; ++q) csr[cbase + st + q] = NN;   // sentinel
  }
}

// ---------------------------------------------------------------- FUSED gather(x) + MFMA MLP layer 1
// Lane (col,quad): quads split neighbors (2 per quad per 8-chunk), 16B x-row
// loads (L2/L3-resident), cross-quad shfl reduce, quad-0 packs A-frag.
// idx<NN guard covers sentinel padding (x is an input; no sentinel row).
__global__ __launch_bounds__(256) void mlp_l1f(
    const float4* __restrict__ x, const int* __restrict__ csr,
    const int2* __restrict__ oc,
    const ushort_t* __restrict__ WaTb,   // bf16 [n][32], zero-padded K
    const float* __restrict__ ba,
    const ushort_t* __restrict__ WbTb,   // bf16 [n][64]
    const float* __restrict__ bb,
    ushort_t* __restrict__ routb,
    float* __restrict__ part) {
  __shared__ __align__(16) ushort_t zt[4096];
  __shared__ float red[512];
  const int tid = threadIdx.x;
  const int wave = tid >> 6, lane = tid & 63;
  const int col = lane & 15, quad = lane >> 4;

  short8 bWa1[4], bWb[2][4];
#pragma unroll
  for (int nt = 0; nt < 4; ++nt) {
    bWa1[nt] = *(const short8*)(WaTb + (nt * 16 + col) * 32 + quad * 8);
#pragma unroll
    for (int k0 = 0; k0 < 2; ++k0)
      bWb[k0][nt] = *(const short8*)(WbTb + (nt * 16 + col) * 64 + k0 * 32 + quad * 8);
  }
  float ba_n[4], bb_n[4];
#pragma unroll
  for (int nt = 0; nt < 4; ++nt) {
    ba_n[nt] = ba[nt * 16 + col];
    bb_n[nt] = bb[nt * 16 + col];
  }

  const int wbase = wave * 1024;
  float scol[4] = {0, 0, 0, 0}, qcol[4] = {0, 0, 0, 0};

  for (int it = 0; it < 8; ++it) {
    const int tile = blockIdx.x * 512 + it * 64 + wave * 16;
    const int row = tile + col;
    const int2 o = oc[row];

    // self (once, quad 0) + neighbors split 2-per-quad per 8-chunk
    float ax = 0.f, ay = 0.f, az_ = 0.f, aw = 0.f;
    if (quad == 0) {
      float4 s = x[row];
      ax = s.x; ay = s.y; az_ = s.z; aw = s.w;
    }
    const int chunks = (o.y + 7) >> 3;
    for (int c = 0; c < chunks; ++c) {
      int2 ij = *(const int2*)(csr + o.x + (c << 3) + (quad << 1));
      if (ij.x < NN) {
        float4 v = x[ij.x];
        ax += v.x; ay += v.y; az_ += v.z; aw += v.w;
      }
      if (ij.y < NN) {
        float4 v = x[ij.y];
        ax += v.x; ay += v.y; az_ += v.z; aw += v.w;
      }
    }
    // cross-quad reduce (lanes col, col+16, col+32, col+48)
    ax += __shfl_xor(ax, 16); ax += __shfl_xor(ax, 32);
    ay += __shfl_xor(ay, 16); ay += __shfl_xor(ay, 32);
    az_ += __shfl_xor(az_, 16); az_ += __shfl_xor(az_, 32);
    aw += __shfl_xor(aw, 16); aw += __shfl_xor(aw, 32);

    f32x4 acc1[4];
#pragma unroll
    for (int nt = 0; nt < 4; ++nt) acc1[nt] = (f32x4){0.f, 0.f, 0.f, 0.f};

    // A-frag: m=col, k=quad*8+j; real data only k<4 (quad 0)
    short8 az = {0, 0, 0, 0, 0, 0, 0, 0};
    if (quad == 0) {
      az[0] = (short)f2bf_bits(ax);
      az[1] = (short)f2bf_bits(ay);
      az[2] = (short)f2bf_bits(az_);
      az[3] = (short)f2bf_bits(aw);
    }
#pragma unroll
    for (int nt = 0; nt < 4; ++nt)
      acc1[nt] = __builtin_amdgcn_mfma_f32_16x16x32_bf16(az, bWa1[nt], acc1[nt], 0, 0, 0);

    // relu -> bf16 -> wave-private swizzled LDS (C-layout write, A-layout read)
#pragma unroll
    for (int nt = 0; nt < 4; ++nt) {
      int oblk = nt * 2 + (col >> 3);
#pragma unroll
      for (int r = 0; r < 4; ++r) {
        int rw = quad * 4 + r;
        float z = fmaxf(acc1[nt][r] + ba_n[nt], 0.0f);
        zt[wbase + rw * 64 + (((oblk ^ (rw & 7)) << 3) | (col & 7))] = f2bf_bits(z);
      }
    }
    short8 az0 = *(const short8*)&zt[wbase + col * 64 + ((quad ^ (col & 7)) << 3)];
    short8 az1 = *(const short8*)&zt[wbase + col * 64 + (((4 + quad) ^ (col & 7)) << 3)];

    f32x4 acc2[4];
#pragma unroll
    for (int nt = 0; nt < 4; ++nt) acc2[nt] = (f32x4){0.f, 0.f, 0.f, 0.f};
#pragma unroll
    for (int nt = 0; nt < 4; ++nt) {
      acc2[nt] = __builtin_amdgcn_mfma_f32_16x16x32_bf16(az0, bWb[0][nt], acc2[nt], 0, 0, 0);
      acc2[nt] = __builtin_amdgcn_mfma_f32_16x16x32_bf16(az1, bWb[1][nt], acc2[nt], 0, 0, 0);
    }
    // relu -> bf16 -> zt repack (same swizzle), then coalesced 32B/lane store
#pragma unroll
    for (int nt = 0; nt < 4; ++nt) {
      int oblk = nt * 2 + (col >> 3);
#pragma unroll
      for (int r = 0; r < 4; ++r) {
        int rw = quad * 4 + r;
        float v = fmaxf(acc2[nt][r] + bb_n[nt], 0.0f);
        zt[wbase + rw * 64 + (((oblk ^ (rw & 7)) << 3) | (col & 7))] = f2bf_bits(v);
        scol[nt] += v; qcol[nt] += v * v;
      }
    }
    {
      const int R = lane >> 2, sp = lane & 3;
      short8 w0 = *(const short8*)&zt[wbase + R * 64 + (((sp * 2) ^ (R & 7)) << 3)];
      short8 w1 = *(const short8*)&zt[wbase + R * 64 + (((sp * 2 + 1) ^ (R & 7)) << 3)];
      ushort_t* dst = routb + (size_t)(tile + R) * 64 + sp * 16;
      *(short8*)dst = w0;
      *(short8*)(dst + 8) = w1;
    }
  }

#pragma unroll
  for (int nt = 0; nt < 4; ++nt) {
    float s = scol[nt], q = qcol[nt];
    s += __shfl_xor(s, 16); s += __shfl_xor(s, 32);
    q += __shfl_xor(q, 16); q += __shfl_xor(q, 32);
    if (quad == 0) {
      red[wave * 128 + nt * 16 + col] = s;
      red[wave * 128 + 64 + nt * 16 + col] = q;
    }
  }
  __syncthreads();
  if (tid < 128)
    part[blockIdx.x * 128 + tid] =
        red[tid] + red[128 + tid] + red[256 + tid] + red[384 + tid];
}

// ---------------------------------------------------------------- FUSED gather + MFMA MLP (L2/L3)
// Grid 992, 512 rows/block, 8 iters (R5-proven config). Register-resident
// weights. GS=false (L2): bf16 row out via zt repack. GS=true (L3):
// segmented register reduction + 8 conflict-free LDS atomics/iter + flush.
template <bool GS>
__global__ __launch_bounds__(256) void mlp_fused(
    const ushort_t* __restrict__ h,
    const int* __restrict__ csr, const int2* __restrict__ oc,
    const float* __restrict__ ss,
    const ushort_t* __restrict__ WaTb,   // bf16 [n][64]
    const float* __restrict__ ba,
    const ushort_t* __restrict__ WbTb,   // bf16 [n][64]
    const float* __restrict__ bb,
    ushort_t* __restrict__ routb, float* __restrict__ gsum_g,
    float* __restrict__ part) {
  __shared__ __align__(16) ushort_t zt[4096];
  __shared__ float red[512];
  __shared__ float ssl[128];
  __shared__ float gsum[GS ? 640 : 1];   // 10 graphs x 64 ch (512-row block)
  const int tid = threadIdx.x;
  const int wave = tid >> 6, lane = tid & 63;
  const int col = lane & 15, quad = lane >> 4;
  if (tid < 128) ssl[tid] = ss[tid];
  const int g0 = (blockIdx.x * 512) / 62;   // first graph touched by block
  if (GS) {
    for (int i = tid; i < 640; i += 256) gsum[i] = 0.0f;
  }

  short8 bWa[2][4], bWb[2][4];
#pragma unroll
  for (int nt = 0; nt < 4; ++nt) {
#pragma unroll
    for (int k0 = 0; k0 < 2; ++k0) {
      bWa[k0][nt] = *(const short8*)(WaTb + (nt * 16 + col) * 64 + k0 * 32 + quad * 8);
      bWb[k0][nt] = *(const short8*)(WbTb + (nt * 16 + col) * 64 + k0 * 32 + quad * 8);
    }
  }
  float ba_n[4], bb_n[4];
#pragma unroll
  for (int nt = 0; nt < 4; ++nt) {
    ba_n[nt] = ba[nt * 16 + col];
    bb_n[nt] = bb[nt * 16 + col];
  }
  __syncthreads();   // ssl (+gsum) ready

  const float* scA = ssl + quad * 8;        // sc channels kA = quad*8+e
  const float* scB = ssl + 32 + quad * 8;   // sc channels kB = 32+quad*8+e
  const float* sfA = ssl + 64 + quad * 8;
  const float* sfB = ssl + 96 + quad * 8;

  const int wbase = wave * 1024;
  float scol[4] = {0, 0, 0, 0}, qcol[4] = {0, 0, 0, 0};

  for (int it = 0; it < 8; ++it) {
    const int tile = blockIdx.x * 512 + it * 64 + wave * 16;
    const int row = tile + col;
    const int2 o = oc[row];

    // self row (eps=0 GIN)
    const ushort_t* hp = h + (size_t)(unsigned)row * 64u + quad * 8;
    short8 sl0 = *(const short8*)hp;
    short8 sl1 = *(const short8*)(hp + 32);
    float accA[8], accB[8];
#pragma unroll
    for (int e = 0; e < 8; ++e) {
      accA[e] = bfu((ushort_t)sl0[e]);
      accB[e] = bfu((ushort_t)sl1[e]);
    }

    const int chunks = (o.y + 7) >> 3;
    for (int c = 0; c < chunks; ++c) {
      const int* cp = csr + o.x + (c << 3);
      int4 i0 = *(const int4*)cp;
      int4 i1 = *(const int4*)(cp + 4);
      int idx[8] = {i0.x, i0.y, i0.z, i0.w, i1.x, i1.y, i1.z, i1.w};
#pragma unroll
      for (int j = 0; j < 8; ++j) {
        const ushort_t* p = h + (size_t)(unsigned)idx[j] * 64u + quad * 8;
        short8 l0 = *(const short8*)p;
        short8 l1 = *(const short8*)(p + 32);
#pragma unroll
        for (int e = 0; e < 8; ++e) {
          accA[e] += bfu((ushort_t)l0[e]);
          accB[e] += bfu((ushort_t)l1[e]);
        }
      }
    }

    // folded BN of previous layer: t = sc*acc + (deg+1)*sf  (sentinels add 0)
    const float m1 = (float)(o.y + 1);
    short8 a0, a1;
#pragma unroll
    for (int e = 0; e < 8; ++e) {
      a0[e] = (short)f2bf_bits(fmaf(scA[e], accA[e], m1 * sfA[e]));
      a1[e] = (short)f2bf_bits(fmaf(scB[e], accB[e], m1 * sfB[e]));
    }

    f32x4 acc1[4];
#pragma unroll
    for (int nt = 0; nt < 4; ++nt) acc1[nt] = (f32x4){0.f, 0.f, 0.f, 0.f};
#pragma unroll
    for (int nt = 0; nt < 4; ++nt) {
      acc1[nt] = __builtin_amdgcn_mfma_f32_16x16x32_bf16(a0, bWa[0][nt], acc1[nt], 0, 0, 0);
      acc1[nt] = __builtin_amdgcn_mfma_f32_16x16x32_bf16(a1, bWa[1][nt], acc1[nt], 0, 0, 0);
    }

    // relu -> bf16 -> wave-private swizzled LDS (C-layout write, A-layout read)
#pragma unroll
    for (int nt = 0; nt < 4; ++nt) {
      int oblk = nt * 2 + (col >> 3);
#pragma unroll
      for (int r = 0; r < 4; ++r) {
        int rw = quad * 4 + r;
        float z = fmaxf(acc1[nt][r] + ba_n[nt], 0.0f);
        zt[wbase + rw * 64 + (((oblk ^ (rw & 7)) << 3) | (col & 7))] = f2bf_bits(z);
      }
    }
    short8 az0 = *(const short8*)&zt[wbase + col * 64 + ((quad ^ (col & 7)) << 3)];
    short8 az1 = *(const short8*)&zt[wbase + col * 64 + (((4 + quad) ^ (col & 7)) << 3)];

    f32x4 acc2[4];
#pragma unroll
    for (int nt = 0; nt < 4; ++nt) acc2[nt] = (f32x4){0.f, 0.f, 0.f, 0.f};
#pragma unroll
    for (int nt = 0; nt < 4; ++nt) {
      acc2[nt] = __builtin_amdgcn_mfma_f32_16x16x32_bf16(az0, bWb[0][nt], acc2[nt], 0, 0, 0);
      acc2[nt] = __builtin_amdgcn_mfma_f32_16x16x32_bf16(az1, bWb[1][nt], acc2[nt], 0, 0, 0);
    }

    if (GS) {
      // segmented per-graph reduction: a wave's 16 rows span <=2 graphs.
      const int gLo = tile / 62;
      const int rEnd = (gLo + 1) * 62;
      float vLo[4], vHi[4];
#pragma unroll
      for (int nt = 0; nt < 4; ++nt) { vLo[nt] = 0.f; vHi[nt] = 0.f; }
#pragma unroll
      for (int nt = 0; nt < 4; ++nt) {
#pragma unroll
        for (int r = 0; r < 4; ++r) {
          int rw = tile + quad * 4 + r;
          float v = fmaxf(acc2[nt][r] + bb_n[nt], 0.0f);
          scol[nt] += v; qcol[nt] += v * v;
          if (rw < rEnd) vLo[nt] += v; else vHi[nt] += v;
        }
      }
#pragma unroll
      for (int nt = 0; nt < 4; ++nt) {
        vLo[nt] += __shfl_xor(vLo[nt], 16); vLo[nt] += __shfl_xor(vLo[nt], 32);
        vHi[nt] += __shfl_xor(vHi[nt], 16); vHi[nt] += __shfl_xor(vHi[nt], 32);
      }
      if (quad == 0) {
        const int gl = gLo - g0;
#pragma unroll
        for (int nt = 0; nt < 4; ++nt) {
          atomicAdd(&gsum[gl * 64 + nt * 16 + col], vLo[nt]);
          atomicAdd(&gsum[(gl + 1) * 64 + nt * 16 + col], vHi[nt]);
        }
      }
    } else {
      // relu -> bf16 -> zt repack, then coalesced 32B/lane store
#pragma unroll
      for (int nt = 0; nt < 4; ++nt) {
        int oblk = nt * 2 + (col >> 3);
#pragma unroll
        for (int r = 0; r < 4; ++r) {
          int rw = quad * 4 + r;
          float v = fmaxf(acc2[nt][r] + bb_n[nt], 0.0f);
          zt[wbase + rw * 64 + (((oblk ^ (rw & 7)) << 3) | (col & 7))] = f2bf_bits(v);
          scol[nt] += v; qcol[nt] += v * v;
        }
      }
      const int R = lane >> 2, sp = lane & 3;
      short8 w0 = *(const short8*)&zt[wbase + R * 64 + (((sp * 2) ^ (R & 7)) << 3)];
      short8 w1 = *(const short8*)&zt[wbase + R * 64 + (((sp * 2 + 1) ^ (R & 7)) << 3)];
      ushort_t* dst = routb + (size_t)(tile + R) * 64 + sp * 16;
      *(short8*)dst = w0;
      *(short8*)(dst + 8) = w1;
    }
  }

#pragma unroll
  for (int nt = 0; nt < 4; ++nt) {
    float s = scol[nt], q = qcol[nt];
    s += __shfl_xor(s, 16); s += __shfl_xor(s, 32);
    q += __shfl_xor(q, 16); q += __shfl_xor(q, 32);
    if (quad == 0) {
      red[wave * 128 + nt * 16 + col] = s;
      red[wave * 128 + 64 + nt * 16 + col] = q;
    }
  }
  __syncthreads();
  if (tid < 128)
    part[blockIdx.x * 128 + tid] =
        red[tid] + red[128 + tid] + red[256 + tid] + red[384 + tid];

  if (GS) {
    // flush per-block graph sums (boundary graphs merged via atomics)
    for (int i = tid; i < 640; i += 256) {
      int g = g0 + (i >> 6);
      float v = gsum[i];
      if (g < NG && v != 0.0f) atomicAdd(&gsum_g[(size_t)g * 64 + (i & 63)], v);
    }
  }
}

// ---------------------------------------------------------------- BN reduce+finalize (merged)
// grid = 64; block c reduces sum (col c) and sumsq (col 64+c), writes ss.
__global__ __launch_bounds__(256) void reduce_finalize(
    const float* __restrict__ part, const float* __restrict__ gma,
    const float* __restrict__ bta, float* __restrict__ ss) {
  __shared__ double sh[512];
  const int c = blockIdx.x, tid = threadIdx.x;
  double a = 0.0, b = 0.0;
  for (int blk = tid; blk < NBLKF; blk += 256) {
    a += (double)part[blk * 128 + c];
    b += (double)part[blk * 128 + 64 + c];
  }
  sh[tid] = a; sh[256 + tid] = b;
  __syncthreads();
  for (int s = 128; s; s >>= 1) {
    if (tid < s) { sh[tid] += sh[tid + s]; sh[256 + tid] += sh[256 + tid + s]; }
    __syncthreads();
  }
  if (tid == 0) {
    double mean = sh[0] / (double)NN;
    double var = sh[256] / (double)NN - mean * mean;
    double sc = (double)gma[c] / sqrt(var + 1e-5);
    ss[c] = (float)sc;
    ss[64 + c] = (float)((double)bta[c] - mean * sc);
  }
}

// ---------------------------------------------------------------- final fc from per-graph sums
// pooled = sc3 * S_g + 62*sf3 ; out = pooled @ Wfc + bfc. 4 graphs/block.
__global__ __launch_bounds__(256) void fc_out(
    const float* __restrict__ gsum_g, const float* __restrict__ ss,
    const float* __restrict__ wfc, const float* __restrict__ bfc,
    float* __restrict__ out) {
  const int lane = threadIdx.x & 63;
  const int g = blockIdx.x * 4 + (threadIdx.x >> 6);
  const int c = lane;
  float s = gsum_g[(size_t)g * 64 + c];
  float pooled = fmaf(ss[c], s, (float)NPG * ss[64 + c]);
#pragma unroll
  for (int j = 0; j < 3; ++j) {
    float v = pooled * wfc[c * 3 + j];
    for (int m = 32; m; m >>= 1) v += __shfl_xor(v, m);
    if (c == 0) out[g * 3 + j] = v + bfc[j];
  }
}

// ---------------------------------------------------------------- launch
extern "C" void kernel_launch(void* const* d_in, const int* in_sizes, int n_in,
                              void* d_out, int out_size, void* d_ws, size_t ws_size,
                              hipStream_t stream) {
  const float* x    = (const float*)d_in[0];
  const int*   srcE = (const int*)d_in[1];
  const int*   dstE = (const int*)d_in[2];
  const float* W1a = (const float*)d_in[4],  *b1a = (const float*)d_in[5];
  const float* W1b = (const float*)d_in[6],  *b1b = (const float*)d_in[7];
  const float* g1  = (const float*)d_in[8],  *be1 = (const float*)d_in[9];
  const float* W2a = (const float*)d_in[10], *b2a = (const float*)d_in[11];
  const float* W2b = (const float*)d_in[12], *b2b = (const float*)d_in[13];
  const float* g2  = (const float*)d_in[14], *be2 = (const float*)d_in[15];
  const float* W3a = (const float*)d_in[16], *b3a = (const float*)d_in[17];
  const float* W3b = (const float*)d_in[18], *b3b = (const float*)d_in[19];
  const float* g3  = (const float*)d_in[20], *be3 = (const float*)d_in[21];
  const float* Wfc = (const float*)d_in[22], *bfc = (const float*)d_in[23];

  float* ws = (float*)d_ws;
  ushort_t* Rb     = (ushort_t*)(ws + OFF_R);    // bf16 rows + sentinel (L1 out)
  float*    GSUM   = ws + OFF_GSUM;              // per-graph sums (L3 out)
  float*    PART   = ws + OFF_PART;
  ushort_t* Ab     = (ushort_t*)(ws + OFF_AGGBF);// bf16 rows + sentinel (L2 out)
  uint2*    RECS   = (uint2*)(ws + OFF_AGGBF);   // alias: dead after p4_build
  int*      CSR    = (int*)(ws + OFF_CSR);
  int2*     OC     = (int2*)(ws + OFF_OC);
  int*      BCUR   = (int*)(ws + OFF_BCUR);
  ushort_t* WTB    = (ushort_t*)(ws + OFF_WTB);
  float*    SS     = ws + OFF_SS;

  // weights + BCUR + sentinels + GSUM zero in one dispatch
  prep_weights<<<519, 256, 0, stream>>>(W1a, W1b, W2a, W2b, W3a, W3b, WTB, BCUR,
                                        (unsigned*)(Rb + (size_t)NN * 64),
                                        (unsigned*)(Ab + (size_t)NN * 64),
                                        GSUM);

  // ---- CSR build (bucket sort, LDS cursors, padded to 8 with sentinel NN)
  p3_bin<<<P3BLK, 256, 0, stream>>>(srcE, dstE, BCUR, RECS);
  p4_build<<<NB, 1024, 0, stream>>>(RECS, BCUR, CSR, OC);

  // ---- layer 1 (fused): gather(x) + MLP -> Rb(bf16)
  mlp_l1f<<<NBLKF, 256, 0, stream>>>((const float4*)x, CSR, OC,
                                     WTB + WB_W1A, b1a, WTB + WB_W1B, b1b,
                                     Rb, PART);
  reduce_finalize<<<64, 256, 0, stream>>>(PART, g1, be1, SS + 0);

  // ---- layer 2 (fused): read Rb (random), write Ab (bf16, coalesced)
  mlp_fused<false><<<NBLKF, 256, 0, stream>>>(Rb, CSR, OC, SS + 0,
                                              WTB + WB_W2A, b2a,
                                              WTB + WB_W2B, b2b,
                                              Ab, nullptr, PART);
  reduce_finalize<<<64, 256, 0, stream>>>(PART, g2, be2, SS + 128);

  // ---- layer 3 (fused): read Ab (random), emit per-graph sums (no row out)
  mlp_fused<true><<<NBLKF, 256, 0, stream>>>(Ab, CSR, OC, SS + 128,
                                             WTB + WB_W3A, b3a,
                                             WTB + WB_W3B, b3b,
                                             nullptr, GSUM, PART);
  reduce_finalize<<<64, 256, 0, stream>>>(PART, g3, be3, SS + 256);

  // ---- classifier from per-graph sums
  fc_out<<<NG / 4, 256, 0, stream>>>(GSUM, SS + 256, Wfc, bfc, (float*)d_out);
}

// Round 11
// 534.248 us; speedup vs baseline: 1.2101x; 1.0103x over previous
//
#include <hip/hip_runtime.h>
#include <hip/hip_bf16.h>

// Problem constants (fixed by the reference)
#define NN   507904          // nodes = 8192*62
#define NE   4063232         // edges = NN*8
#define NG   8192            // graphs
#define NPG  62              // nodes per graph
#define NBLKF 992            // NN/512 (mlp grid; 512 rows/block, 8 iters; R5-proven)

// Bucket sort parameters
#define NB    248            // buckets = NN/2048 (exact)
#define BRNG  2048           // nodes per bucket (bucket = dst>>11)
#define BCAP  17152          // bucket record capacity (mean 16384, +6 sigma)
#define PBCAP 31744          // padded csr capacity/bucket (8-aligned)
#define P3BLK 992            // NE/4096 (exact)
#define CSRSZ (NB * PBCAP)   // 7,872,512 ints

// ---------------------------------------------------------------- ws layout (4B units)
// OFF_R region (NN*64 units) is multiplexed:
//   [0, NN*32)              Rb bf16 rows (L1 out)
//   [NN*32, +32)            Rb sentinel row
//   OFF_GSUM (NG*64)        per-graph fp32 sums (L3 out)
//   OFF_PART (NBLKF*128)    BN partials
#define OFF_R     0
#define OFF_GSUM  (OFF_R + NN * 32 + 64)
#define OFF_PART  (OFF_GSUM + NG * 64)
#define OFF_AGGBF (OFF_R + NN * 64)          // Ab bf16 rows (+sentinel) | alias: RECS
#define OFF_CSR   (OFF_AGGBF + NN * 32 + 32) // CSRSZ ints (padded CSR)
#define OFF_OC    (OFF_CSR + CSRSZ)          // NN int2 (off,deg)
#define OFF_BCUR  (OFF_OC + 2 * NN)          // 256 ints
#define OFF_WTB   (OFF_BCUR + 256)           // bf16 weights: 22528 ushort = 11264 units
#define OFF_SS    (OFF_WTB + 11264)          // 3 x (scale[64], shift[64])

// bf16 weight offsets (ushort units)
#define WB_W1B 0
#define WB_W2A 4096
#define WB_W2B 8192
#define WB_W3A 12288
#define WB_W3B 16384
#define WB_W1A 20480         // 64 x 32, zero-padded K (only k<4 nonzero)

typedef __attribute__((ext_vector_type(8))) short short8;
typedef __attribute__((ext_vector_type(4))) float f32x4;
typedef unsigned short ushort_t;

__device__ __forceinline__ ushort_t f2bf_bits(float f) {
  union { float f; unsigned u; } x; x.f = f;
  unsigned r = x.u + 0x7FFF + ((x.u >> 16) & 1);
  return (ushort_t)(r >> 16);
}
__device__ __forceinline__ float bfu(ushort_t u) {
  union { unsigned i; float f; } x; x.i = ((unsigned)u) << 16; return x.f;
}

// ---------------------------------------------------------------- weight prep + zero-inits
__global__ __launch_bounds__(256) void prep_weights(
    const float* __restrict__ w1a, const float* __restrict__ w1b,
    const float* __restrict__ w2a, const float* __restrict__ w2b,
    const float* __restrict__ w3a, const float* __restrict__ w3b,
    ushort_t* __restrict__ wtb, int* __restrict__ bcur,
    unsigned* __restrict__ sent1, unsigned* __restrict__ sent2,
    float* __restrict__ gsum) {
  int b = blockIdx.x, tid = threadIdx.x;
  if (b == 0) {
    // W1a [4][64] -> bf16 [n][32], zero-padded K (k<4 nonzero)
    ushort_t* d = wtb + WB_W1A;
    for (int i = tid; i < 2048; i += 256) {
      int n = i >> 5, k = i & 31;
      d[i] = (k < 4) ? f2bf_bits(w1a[k * 64 + n]) : (ushort_t)0;
    }
  } else if (b == 6) {
    bcur[tid] = 0;                       // 256 ints
    if (tid < 32) { sent1[tid] = 0; sent2[tid] = 0; }   // sentinel rows
  } else if (b >= 7) {
    // zero GSUM: 512 blocks x 1024 floats = NG*64
    float* g = gsum + (size_t)(b - 7) * 1024;
#pragma unroll
    for (int k = 0; k < 4; ++k) g[k * 256 + tid] = 0.0f;
  } else {
    const float* s; ushort_t* d;
    switch (b) {
      case 1: s = w1b; d = wtb + WB_W1B; break;
      case 2: s = w2a; d = wtb + WB_W2A; break;
      case 3: s = w2b; d = wtb + WB_W2B; break;
      case 4: s = w3a; d = wtb + WB_W3A; break;
      default: s = w3b; d = wtb + WB_W3B; break;
    }
    for (int i = tid; i < 4096; i += 256) {
      int k = i >> 6, n = i & 63;              // src [k][n]
      d[n * 64 + k] = f2bf_bits(s[i]);         // dst [n][k]
    }
  }
}

// ---------------------------------------------------------------- CSR build: phase 1
// Packed global records: rec = src(19b) | localdst(11b)<<19  (NN < 2^19,
// BRNG = 2048 = 2^11). LDS buf keeps full (dst,src) so the scatter can
// recover the bucket id; only the global round-trip is halved (32->16 MB).
__global__ __launch_bounds__(256) void p3_bin(
    const int* __restrict__ src, const int* __restrict__ dst,
    int* __restrict__ bcur, unsigned* __restrict__ recs) {
  __shared__ int histo[256];
  __shared__ int scan_s[256];
  __shared__ int base_s[256];
  __shared__ int cur_s[256];
  __shared__ uint2 buf[4096];
  const int tid = threadIdx.x;
  const int e0 = blockIdx.x * 4096;

  histo[tid] = 0;
  __syncthreads();

  int d_[16], s_[16];
#pragma unroll
  for (int k = 0; k < 16; ++k) {
    int e = e0 + k * 256 + tid;
    d_[k] = dst[e]; s_[k] = src[e];
    atomicAdd(&histo[d_[k] >> 11], 1);
  }
  __syncthreads();

  int v = histo[tid];
  scan_s[tid] = v; __syncthreads();
  for (int s = 1; s < 256; s <<= 1) {
    int add = (tid >= s) ? scan_s[tid - s] : 0;
    __syncthreads();
    scan_s[tid] += add;
    __syncthreads();
  }
  int excl = scan_s[tid] - v;
  if (tid < NB) base_s[tid] = atomicAdd(&bcur[tid], v);
  cur_s[tid] = excl;
  histo[tid] = excl;
  __syncthreads();

#pragma unroll
  for (int k = 0; k < 16; ++k) {
    int b = d_[k] >> 11;
    int p = atomicAdd(&cur_s[b], 1);
    uint2 r; r.x = (unsigned)d_[k]; r.y = (unsigned)s_[k];
    buf[p] = r;
  }
  __syncthreads();

  for (int i = tid; i < 4096; i += 256) {
    uint2 r = buf[i];
    int b = (int)(r.x >> 11);
    int g = base_s[b] + (i - histo[b]);
    if (g < BCAP)
      recs[(size_t)b * BCAP + g] = (r.y & 0x7FFFFu) | ((r.x & 2047u) << 19);
  }
}

// ---------------------------------------------------------------- CSR build: phase 2 (packed recs)
__global__ __launch_bounds__(1024) void p4_build(
    const unsigned* __restrict__ recs, const int* __restrict__ bcur,
    int* __restrict__ csr, int2* __restrict__ oc) {
  __shared__ int lcnt[2048];
  __shared__ int pscan[1024];
  __shared__ int sstart[2048];
  __shared__ int scur[2048];
  const int b = blockIdx.x, tid = threadIdx.x;
  int m = bcur[b]; if (m > BCAP) m = BCAP;
  const int cbase = b * PBCAP;
  const int nbase = b << 11;
  const unsigned* rp = recs + (size_t)b * BCAP;

  lcnt[tid] = 0; lcnt[1024 + tid] = 0;
  __syncthreads();
  for (int i = tid; i < m; i += 1024)
    atomicAdd(&lcnt[(rp[i] >> 19) & 2047u], 1);
  __syncthreads();

  int a0 = lcnt[2 * tid], a1 = lcnt[2 * tid + 1];
  int p0 = (a0 + 7) & ~7, p1 = (a1 + 7) & ~7;
  int ps = p0 + p1;
  pscan[tid] = ps; __syncthreads();
  for (int s = 1; s < 1024; s <<= 1) {
    int add = (tid >= s) ? pscan[tid - s] : 0;
    __syncthreads();
    pscan[tid] += add;
    __syncthreads();
  }
  int e0 = pscan[tid] - ps;
  sstart[2 * tid] = e0;          scur[2 * tid] = e0;
  sstart[2 * tid + 1] = e0 + p0; scur[2 * tid + 1] = e0 + p0;
  __syncthreads();

  // packed (off,deg) records
  {
    int2 r0; r0.x = cbase + sstart[tid];        r0.y = lcnt[tid];
    int2 r1; r1.x = cbase + sstart[1024 + tid]; r1.y = lcnt[1024 + tid];
    oc[nbase + tid] = r0;
    oc[nbase + 1024 + tid] = r1;
  }
  __syncthreads();

  for (int i = tid; i < m; i += 1024) {
    unsigned r = rp[i];
    int p = atomicAdd(&scur[(r >> 19) & 2047u], 1);
    csr[cbase + p] = (int)(r & 0x7FFFFu);
  }
  __syncthreads();

#pragma unroll
  for (int k = 0; k < 2; ++k) {
    int i = k * 1024 + tid;
    int st = sstart[i], d = lcnt[i], p = (d + 7) & ~7;
    for (int q = d; q < p; ++q) csr[cbase + st + q] = NN;   // sentinel
  }
}

// ---------------------------------------------------------------- FUSED gather(x) + MFMA MLP layer 1
// Lane (col,quad): quads split neighbors (2 per quad per 8-chunk), 16B x-row
// loads (L2/L3-resident), cross-quad shfl reduce, quad-0 packs A-frag.
// idx<NN guard covers sentinel padding (x is an input; no sentinel row).
__global__ __launch_bounds__(256) void mlp_l1f(
    const float4* __restrict__ x, const int* __restrict__ csr,
    const int2* __restrict__ oc,
    const ushort_t* __restrict__ WaTb,   // bf16 [n][32], zero-padded K
    const float* __restrict__ ba,
    const ushort_t* __restrict__ WbTb,   // bf16 [n][64]
    const float* __restrict__ bb,
    ushort_t* __restrict__ routb,
    float* __restrict__ part) {
  __shared__ __align__(16) ushort_t zt[4096];
  __shared__ float red[512];
  const int tid = threadIdx.x;
  const int wave = tid >> 6, lane = tid & 63;
  const int col = lane & 15, quad = lane >> 4;

  short8 bWa1[4], bWb[2][4];
#pragma unroll
  for (int nt = 0; nt < 4; ++nt) {
    bWa1[nt] = *(const short8*)(WaTb + (nt * 16 + col) * 32 + quad * 8);
#pragma unroll
    for (int k0 = 0; k0 < 2; ++k0)
      bWb[k0][nt] = *(const short8*)(WbTb + (nt * 16 + col) * 64 + k0 * 32 + quad * 8);
  }
  float ba_n[4], bb_n[4];
#pragma unroll
  for (int nt = 0; nt < 4; ++nt) {
    ba_n[nt] = ba[nt * 16 + col];
    bb_n[nt] = bb[nt * 16 + col];
  }

  const int wbase = wave * 1024;
  float scol[4] = {0, 0, 0, 0}, qcol[4] = {0, 0, 0, 0};

  for (int it = 0; it < 8; ++it) {
    const int tile = blockIdx.x * 512 + it * 64 + wave * 16;
    const int row = tile + col;
    const int2 o = oc[row];

    // self (once, quad 0) + neighbors split 2-per-quad per 8-chunk
    float ax = 0.f, ay = 0.f, az_ = 0.f, aw = 0.f;
    if (quad == 0) {
      float4 s = x[row];
      ax = s.x; ay = s.y; az_ = s.z; aw = s.w;
    }
    const int chunks = (o.y + 7) >> 3;
    for (int c = 0; c < chunks; ++c) {
      int2 ij = *(const int2*)(csr + o.x + (c << 3) + (quad << 1));
      if (ij.x < NN) {
        float4 v = x[ij.x];
        ax += v.x; ay += v.y; az_ += v.z; aw += v.w;
      }
      if (ij.y < NN) {
        float4 v = x[ij.y];
        ax += v.x; ay += v.y; az_ += v.z; aw += v.w;
      }
    }
    // cross-quad reduce (lanes col, col+16, col+32, col+48)
    ax += __shfl_xor(ax, 16); ax += __shfl_xor(ax, 32);
    ay += __shfl_xor(ay, 16); ay += __shfl_xor(ay, 32);
    az_ += __shfl_xor(az_, 16); az_ += __shfl_xor(az_, 32);
    aw += __shfl_xor(aw, 16); aw += __shfl_xor(aw, 32);

    f32x4 acc1[4];
#pragma unroll
    for (int nt = 0; nt < 4; ++nt) acc1[nt] = (f32x4){0.f, 0.f, 0.f, 0.f};

    // A-frag: m=col, k=quad*8+j; real data only k<4 (quad 0)
    short8 az = {0, 0, 0, 0, 0, 0, 0, 0};
    if (quad == 0) {
      az[0] = (short)f2bf_bits(ax);
      az[1] = (short)f2bf_bits(ay);
      az[2] = (short)f2bf_bits(az_);
      az[3] = (short)f2bf_bits(aw);
    }
#pragma unroll
    for (int nt = 0; nt < 4; ++nt)
      acc1[nt] = __builtin_amdgcn_mfma_f32_16x16x32_bf16(az, bWa1[nt], acc1[nt], 0, 0, 0);

    // relu -> bf16 -> wave-private swizzled LDS (C-layout write, A-layout read)
#pragma unroll
    for (int nt = 0; nt < 4; ++nt) {
      int oblk = nt * 2 + (col >> 3);
#pragma unroll
      for (int r = 0; r < 4; ++r) {
        int rw = quad * 4 + r;
        float z = fmaxf(acc1[nt][r] + ba_n[nt], 0.0f);
        zt[wbase + rw * 64 + (((oblk ^ (rw & 7)) << 3) | (col & 7))] = f2bf_bits(z);
      }
    }
    short8 az0 = *(const short8*)&zt[wbase + col * 64 + ((quad ^ (col & 7)) << 3)];
    short8 az1 = *(const short8*)&zt[wbase + col * 64 + (((4 + quad) ^ (col & 7)) << 3)];

    f32x4 acc2[4];
#pragma unroll
    for (int nt = 0; nt < 4; ++nt) acc2[nt] = (f32x4){0.f, 0.f, 0.f, 0.f};
#pragma unroll
    for (int nt = 0; nt < 4; ++nt) {
      acc2[nt] = __builtin_amdgcn_mfma_f32_16x16x32_bf16(az0, bWb[0][nt], acc2[nt], 0, 0, 0);
      acc2[nt] = __builtin_amdgcn_mfma_f32_16x16x32_bf16(az1, bWb[1][nt], acc2[nt], 0, 0, 0);
    }
    // relu -> bf16 -> zt repack (same swizzle), then coalesced 32B/lane store
#pragma unroll
    for (int nt = 0; nt < 4; ++nt) {
      int oblk = nt * 2 + (col >> 3);
#pragma unroll
      for (int r = 0; r < 4; ++r) {
        int rw = quad * 4 + r;
        float v = fmaxf(acc2[nt][r] + bb_n[nt], 0.0f);
        zt[wbase + rw * 64 + (((oblk ^ (rw & 7)) << 3) | (col & 7))] = f2bf_bits(v);
        scol[nt] += v; qcol[nt] += v * v;
      }
    }
    {
      const int R = lane >> 2, sp = lane & 3;
      short8 w0 = *(const short8*)&zt[wbase + R * 64 + (((sp * 2) ^ (R & 7)) << 3)];
      short8 w1 = *(const short8*)&zt[wbase + R * 64 + (((sp * 2 + 1) ^ (R & 7)) << 3)];
      ushort_t* dst = routb + (size_t)(tile + R) * 64 + sp * 16;
      *(short8*)dst = w0;
      *(short8*)(dst + 8) = w1;
    }
  }

#pragma unroll
  for (int nt = 0; nt < 4; ++nt) {
    float s = scol[nt], q = qcol[nt];
    s += __shfl_xor(s, 16); s += __shfl_xor(s, 32);
    q += __shfl_xor(q, 16); q += __shfl_xor(q, 32);
    if (quad == 0) {
      red[wave * 128 + nt * 16 + col] = s;
      red[wave * 128 + 64 + nt * 16 + col] = q;
    }
  }
  __syncthreads();
  if (tid < 128)
    part[blockIdx.x * 128 + tid] =
        red[tid] + red[128 + tid] + red[256 + tid] + red[384 + tid];
}

// ---------------------------------------------------------------- FUSED gather + MFMA MLP (L2/L3)
// Grid 992, 512 rows/block, 8 iters (R5-proven config). Register-resident
// weights. GS=false (L2): bf16 row out via zt repack. GS=true (L3):
// segmented register reduction + 8 conflict-free LDS atomics/iter + flush.
template <bool GS>
__global__ __launch_bounds__(256) void mlp_fused(
    const ushort_t* __restrict__ h,
    const int* __restrict__ csr, const int2* __restrict__ oc,
    const float* __restrict__ ss,
    const ushort_t* __restrict__ WaTb,   // bf16 [n][64]
    const float* __restrict__ ba,
    const ushort_t* __restrict__ WbTb,   // bf16 [n][64]
    const float* __restrict__ bb,
    ushort_t* __restrict__ routb, float* __restrict__ gsum_g,
    float* __restrict__ part) {
  __shared__ __align__(16) ushort_t zt[4096];
  __shared__ float red[512];
  __shared__ float ssl[128];
  __shared__ float gsum[GS ? 640 : 1];   // 10 graphs x 64 ch (512-row block)
  const int tid = threadIdx.x;
  const int wave = tid >> 6, lane = tid & 63;
  const int col = lane & 15, quad = lane >> 4;
  if (tid < 128) ssl[tid] = ss[tid];
  const int g0 = (blockIdx.x * 512) / 62;   // first graph touched by block
  if (GS) {
    for (int i = tid; i < 640; i += 256) gsum[i] = 0.0f;
  }

  short8 bWa[2][4], bWb[2][4];
#pragma unroll
  for (int nt = 0; nt < 4; ++nt) {
#pragma unroll
    for (int k0 = 0; k0 < 2; ++k0) {
      bWa[k0][nt] = *(const short8*)(WaTb + (nt * 16 + col) * 64 + k0 * 32 + quad * 8);
      bWb[k0][nt] = *(const short8*)(WbTb + (nt * 16 + col) * 64 + k0 * 32 + quad * 8);
    }
  }
  float ba_n[4], bb_n[4];
#pragma unroll
  for (int nt = 0; nt < 4; ++nt) {
    ba_n[nt] = ba[nt * 16 + col];
    bb_n[nt] = bb[nt * 16 + col];
  }
  __syncthreads();   // ssl (+gsum) ready

  const float* scA = ssl + quad * 8;        // sc channels kA = quad*8+e
  const float* scB = ssl + 32 + quad * 8;   // sc channels kB = 32+quad*8+e
  const float* sfA = ssl + 64 + quad * 8;
  const float* sfB = ssl + 96 + quad * 8;

  const int wbase = wave * 1024;
  float scol[4] = {0, 0, 0, 0}, qcol[4] = {0, 0, 0, 0};

  for (int it = 0; it < 8; ++it) {
    const int tile = blockIdx.x * 512 + it * 64 + wave * 16;
    const int row = tile + col;
    const int2 o = oc[row];

    // self row (eps=0 GIN)
    const ushort_t* hp = h + (size_t)(unsigned)row * 64u + quad * 8;
    short8 sl0 = *(const short8*)hp;
    short8 sl1 = *(const short8*)(hp + 32);
    float accA[8], accB[8];
#pragma unroll
    for (int e = 0; e < 8; ++e) {
      accA[e] = bfu((ushort_t)sl0[e]);
      accB[e] = bfu((ushort_t)sl1[e]);
    }

    const int chunks = (o.y + 7) >> 3;
    for (int c = 0; c < chunks; ++c) {
      const int* cp = csr + o.x + (c << 3);
      int4 i0 = *(const int4*)cp;
      int4 i1 = *(const int4*)(cp + 4);
      int idx[8] = {i0.x, i0.y, i0.z, i0.w, i1.x, i1.y, i1.z, i1.w};
#pragma unroll
      for (int j = 0; j < 8; ++j) {
        const ushort_t* p = h + (size_t)(unsigned)idx[j] * 64u + quad * 8;
        short8 l0 = *(const short8*)p;
        short8 l1 = *(const short8*)(p + 32);
#pragma unroll
        for (int e = 0; e < 8; ++e) {
          accA[e] += bfu((ushort_t)l0[e]);
          accB[e] += bfu((ushort_t)l1[e]);
        }
      }
    }

    // folded BN of previous layer: t = sc*acc + (deg+1)*sf  (sentinels add 0)
    const float m1 = (float)(o.y + 1);
    short8 a0, a1;
#pragma unroll
    for (int e = 0; e < 8; ++e) {
      a0[e] = (short)f2bf_bits(fmaf(scA[e], accA[e], m1 * sfA[e]));
      a1[e] = (short)f2bf_bits(fmaf(scB[e], accB[e], m1 * sfB[e]));
    }

    f32x4 acc1[4];
#pragma unroll
    for (int nt = 0; nt < 4; ++nt) acc1[nt] = (f32x4){0.f, 0.f, 0.f, 0.f};
#pragma unroll
    for (int nt = 0; nt < 4; ++nt) {
      acc1[nt] = __builtin_amdgcn_mfma_f32_16x16x32_bf16(a0, bWa[0][nt], acc1[nt], 0, 0, 0);
      acc1[nt] = __builtin_amdgcn_mfma_f32_16x16x32_bf16(a1, bWa[1][nt], acc1[nt], 0, 0, 0);
    }

    // relu -> bf16 -> wave-private swizzled LDS (C-layout write, A-layout read)
#pragma unroll
    for (int nt = 0; nt < 4; ++nt) {
      int oblk = nt * 2 + (col >> 3);
#pragma unroll
      for (int r = 0; r < 4; ++r) {
        int rw = quad * 4 + r;
        float z = fmaxf(acc1[nt][r] + ba_n[nt], 0.0f);
        zt[wbase + rw * 64 + (((oblk ^ (rw & 7)) << 3) | (col & 7))] = f2bf_bits(z);
      }
    }
    short8 az0 = *(const short8*)&zt[wbase + col * 64 + ((quad ^ (col & 7)) << 3)];
    short8 az1 = *(const short8*)&zt[wbase + col * 64 + (((4 + quad) ^ (col & 7)) << 3)];

    f32x4 acc2[4];
#pragma unroll
    for (int nt = 0; nt < 4; ++nt) acc2[nt] = (f32x4){0.f, 0.f, 0.f, 0.f};
#pragma unroll
    for (int nt = 0; nt < 4; ++nt) {
      acc2[nt] = __builtin_amdgcn_mfma_f32_16x16x32_bf16(az0, bWb[0][nt], acc2[nt], 0, 0, 0);
      acc2[nt] = __builtin_amdgcn_mfma_f32_16x16x32_bf16(az1, bWb[1][nt], acc2[nt], 0, 0, 0);
    }

    if (GS) {
      // segmented per-graph reduction: a wave's 16 rows span <=2 graphs.
      const int gLo = tile / 62;
      const int rEnd = (gLo + 1) * 62;
      float vLo[4], vHi[4];
#pragma unroll
      for (int nt = 0; nt < 4; ++nt) { vLo[nt] = 0.f; vHi[nt] = 0.f; }
#pragma unroll
      for (int nt = 0; nt < 4; ++nt) {
#pragma unroll
        for (int r = 0; r < 4; ++r) {
          int rw = tile + quad * 4 + r;
          float v = fmaxf(acc2[nt][r] + bb_n[nt], 0.0f);
          scol[nt] += v; qcol[nt] += v * v;
          if (rw < rEnd) vLo[nt] += v; else vHi[nt] += v;
        }
      }
#pragma unroll
      for (int nt = 0; nt < 4; ++nt) {
        vLo[nt] += __shfl_xor(vLo[nt], 16); vLo[nt] += __shfl_xor(vLo[nt], 32);
        vHi[nt] += __shfl_xor(vHi[nt], 16); vHi[nt] += __shfl_xor(vHi[nt], 32);
      }
      if (quad == 0) {
        const int gl = gLo - g0;
#pragma unroll
        for (int nt = 0; nt < 4; ++nt) {
          atomicAdd(&gsum[gl * 64 + nt * 16 + col], vLo[nt]);
          atomicAdd(&gsum[(gl + 1) * 64 + nt * 16 + col], vHi[nt]);
        }
      }
    } else {
      // relu -> bf16 -> zt repack, then coalesced 32B/lane store
#pragma unroll
      for (int nt = 0; nt < 4; ++nt) {
        int oblk = nt * 2 + (col >> 3);
#pragma unroll
        for (int r = 0; r < 4; ++r) {
          int rw = quad * 4 + r;
          float v = fmaxf(acc2[nt][r] + bb_n[nt], 0.0f);
          zt[wbase + rw * 64 + (((oblk ^ (rw & 7)) << 3) | (col & 7))] = f2bf_bits(v);
          scol[nt] += v; qcol[nt] += v * v;
        }
      }
      const int R = lane >> 2, sp = lane & 3;
      short8 w0 = *(const short8*)&zt[wbase + R * 64 + (((sp * 2) ^ (R & 7)) << 3)];
      short8 w1 = *(const short8*)&zt[wbase + R * 64 + (((sp * 2 + 1) ^ (R & 7)) << 3)];
      ushort_t* dst = routb + (size_t)(tile + R) * 64 + sp * 16;
      *(short8*)dst = w0;
      *(short8*)(dst + 8) = w1;
    }
  }

#pragma unroll
  for (int nt = 0; nt < 4; ++nt) {
    float s = scol[nt], q = qcol[nt];
    s += __shfl_xor(s, 16); s += __shfl_xor(s, 32);
    q += __shfl_xor(q, 16); q += __shfl_xor(q, 32);
    if (quad == 0) {
      red[wave * 128 + nt * 16 + col] = s;
      red[wave * 128 + 64 + nt * 16 + col] = q;
    }
  }
  __syncthreads();
  if (tid < 128)
    part[blockIdx.x * 128 + tid] =
        red[tid] + red[128 + tid] + red[256 + tid] + red[384 + tid];

  if (GS) {
    // flush per-block graph sums (boundary graphs merged via atomics)
    for (int i = tid; i < 640; i += 256) {
      int g = g0 + (i >> 6);
      float v = gsum[i];
      if (g < NG && v != 0.0f) atomicAdd(&gsum_g[(size_t)g * 64 + (i & 63)], v);
    }
  }
}

// ---------------------------------------------------------------- BN reduce+finalize (merged)
// grid = 64; block c reduces sum (col c) and sumsq (col 64+c), writes ss.
__global__ __launch_bounds__(256) void reduce_finalize(
    const float* __restrict__ part, const float* __restrict__ gma,
    const float* __restrict__ bta, float* __restrict__ ss) {
  __shared__ double sh[512];
  const int c = blockIdx.x, tid = threadIdx.x;
  double a = 0.0, b = 0.0;
  for (int blk = tid; blk < NBLKF; blk += 256) {
    a += (double)part[blk * 128 + c];
    b += (double)part[blk * 128 + 64 + c];
  }
  sh[tid] = a; sh[256 + tid] = b;
  __syncthreads();
  for (int s = 128; s; s >>= 1) {
    if (tid < s) { sh[tid] += sh[tid + s]; sh[256 + tid] += sh[256 + tid + s]; }
    __syncthreads();
  }
  if (tid == 0) {
    double mean = sh[0] / (double)NN;
    double var = sh[256] / (double)NN - mean * mean;
    double sc = (double)gma[c] / sqrt(var + 1e-5);
    ss[c] = (float)sc;
    ss[64 + c] = (float)((double)bta[c] - mean * sc);
  }
}

// ---------------------------------------------------------------- final fc from per-graph sums
// pooled = sc3 * S_g + 62*sf3 ; out = pooled @ Wfc + bfc. 4 graphs/block.
__global__ __launch_bounds__(256) void fc_out(
    const float* __restrict__ gsum_g, const float* __restrict__ ss,
    const float* __restrict__ wfc, const float* __restrict__ bfc,
    float* __restrict__ out) {
  const int lane = threadIdx.x & 63;
  const int g = blockIdx.x * 4 + (threadIdx.x >> 6);
  const int c = lane;
  float s = gsum_g[(size_t)g * 64 + c];
  float pooled = fmaf(ss[c], s, (float)NPG * ss[64 + c]);
#pragma unroll
  for (int j = 0; j < 3; ++j) {
    float v = pooled * wfc[c * 3 + j];
    for (int m = 32; m; m >>= 1) v += __shfl_xor(v, m);
    if (c == 0) out[g * 3 + j] = v + bfc[j];
  }
}

// ---------------------------------------------------------------- launch
extern "C" void kernel_launch(void* const* d_in, const int* in_sizes, int n_in,
                              void* d_out, int out_size, void* d_ws, size_t ws_size,
                              hipStream_t stream) {
  const float* x    = (const float*)d_in[0];
  const int*   srcE = (const int*)d_in[1];
  const int*   dstE = (const int*)d_in[2];
  const float* W1a = (const float*)d_in[4],  *b1a = (const float*)d_in[5];
  const float* W1b = (const float*)d_in[6],  *b1b = (const float*)d_in[7];
  const float* g1  = (const float*)d_in[8],  *be1 = (const float*)d_in[9];
  const float* W2a = (const float*)d_in[10], *b2a = (const float*)d_in[11];
  const float* W2b = (const float*)d_in[12], *b2b = (const float*)d_in[13];
  const float* g2  = (const float*)d_in[14], *be2 = (const float*)d_in[15];
  const float* W3a = (const float*)d_in[16], *b3a = (const float*)d_in[17];
  const float* W3b = (const float*)d_in[18], *b3b = (const float*)d_in[19];
  const float* g3  = (const float*)d_in[20], *be3 = (const float*)d_in[21];
  const float* Wfc = (const float*)d_in[22], *bfc = (const float*)d_in[23];

  float* ws = (float*)d_ws;
  ushort_t* Rb     = (ushort_t*)(ws + OFF_R);    // bf16 rows + sentinel (L1 out)
  float*    GSUM   = ws + OFF_GSUM;              // per-graph sums (L3 out)
  float*    PART   = ws + OFF_PART;
  ushort_t* Ab     = (ushort_t*)(ws + OFF_AGGBF);// bf16 rows + sentinel (L2 out)
  unsigned* RECS   = (unsigned*)(ws + OFF_AGGBF);// alias: dead after p4_build
  int*      CSR    = (int*)(ws + OFF_CSR);
  int2*     OC     = (int2*)(ws + OFF_OC);
  int*      BCUR   = (int*)(ws + OFF_BCUR);
  ushort_t* WTB    = (ushort_t*)(ws + OFF_WTB);
  float*    SS     = ws + OFF_SS;

  // weights + BCUR + sentinels + GSUM zero in one dispatch
  prep_weights<<<519, 256, 0, stream>>>(W1a, W1b, W2a, W2b, W3a, W3b, WTB, BCUR,
                                        (unsigned*)(Rb + (size_t)NN * 64),
                                        (unsigned*)(Ab + (size_t)NN * 64),
                                        GSUM);

  // ---- CSR build (bucket sort, packed recs, padded to 8 with sentinel NN)
  p3_bin<<<P3BLK, 256, 0, stream>>>(srcE, dstE, BCUR, RECS);
  p4_build<<<NB, 1024, 0, stream>>>(RECS, BCUR, CSR, OC);

  // ---- layer 1 (fused): gather(x) + MLP -> Rb(bf16)
  mlp_l1f<<<NBLKF, 256, 0, stream>>>((const float4*)x, CSR, OC,
                                     WTB + WB_W1A, b1a, WTB + WB_W1B, b1b,
                                     Rb, PART);
  reduce_finalize<<<64, 256, 0, stream>>>(PART, g1, be1, SS + 0);

  // ---- layer 2 (fused): read Rb (random), write Ab (bf16, coalesced)
  mlp_fused<false><<<NBLKF, 256, 0, stream>>>(Rb, CSR, OC, SS + 0,
                                              WTB + WB_W2A, b2a,
                                              WTB + WB_W2B, b2b,
                                              Ab, nullptr, PART);
  reduce_finalize<<<64, 256, 0, stream>>>(PART, g2, be2, SS + 128);

  // ---- layer 3 (fused): read Ab (random), emit per-graph sums (no row out)
  mlp_fused<true><<<NBLKF, 256, 0, stream>>>(Ab, CSR, OC, SS + 128,
                                             WTB + WB_W3A, b3a,
                                             WTB + WB_W3B, b3b,
                                             nullptr, GSUM, PART);
  reduce_finalize<<<64, 256, 0, stream>>>(PART, g3, be3, SS + 256);

  // ---- classifier from per-graph sums
  fc_out<<<NG / 4, 256, 0, stream>>>(GSUM, SS + 256, Wfc, bfc, (float*)d_out);
}